// Round 8
// baseline (507.830 us; speedup 1.0000x reference)
//
#include <hip/hip_runtime.h>
#include <math.h>

#define Lh 2304
#define Ch 768
#define NHh 12
#define Bh 2
#define QS 4608   // row stride of fused qkv activation buffer (global q|k|v, local q|k|v)

typedef unsigned short ushort_t;
typedef unsigned int uint_t;
typedef __attribute__((ext_vector_type(8))) short bf16x8;
typedef __attribute__((ext_vector_type(4))) float f32x4;
#define MFMA16(a, b, c) __builtin_amdgcn_mfma_f32_16x16x32_bf16(a, b, c, 0, 0, 0)

__device__ __forceinline__ ushort_t f2bf(float f) {
    union { float f; uint_t u; } v; v.f = f;
    uint_t u = v.u + 0x7fffu + ((v.u >> 16) & 1u);   // RNE
    return (ushort_t)(u >> 16);
}

// async global->LDS, 16B/lane, dest = wave-uniform base + lane*16
__device__ __forceinline__ void llds16(ushort_t* dst, const ushort_t* src) {
    __builtin_amdgcn_global_load_lds(
        (__attribute__((address_space(1))) void*)(const_cast<ushort_t*>(src)),
        (__attribute__((address_space(3))) void*)dst, 16, 0, 0);
}

// ---------------------------------------------------------------- layernorm (fp32 in, bf16 out)
__global__ __launch_bounds__(256)
void layernorm_bf16_kernel(const float* __restrict__ x, const float* __restrict__ w,
                           const float* __restrict__ b, ushort_t* __restrict__ y)
{
    int row = blockIdx.x;
    int tid = threadIdx.x;
    const float* xr = x + (size_t)row * Ch;
    float v0 = xr[tid], v1 = xr[tid + 256], v2 = xr[tid + 512];
    __shared__ float red[256];
    red[tid] = v0 + v1 + v2;
    __syncthreads();
    for (int st = 128; st > 0; st >>= 1) {
        if (tid < st) red[tid] += red[tid + st];
        __syncthreads();
    }
    float mean = red[0] * (1.0f / 768.0f);
    __syncthreads();
    float d0 = v0 - mean, d1 = v1 - mean, d2 = v2 - mean;
    red[tid] = d0 * d0 + d1 * d1 + d2 * d2;
    __syncthreads();
    for (int st = 128; st > 0; st >>= 1) {
        if (tid < st) red[tid] += red[tid + st];
        __syncthreads();
    }
    float rstd = rsqrtf(red[0] * (1.0f / 768.0f) + 1e-6f);
    ushort_t* yr = y + (size_t)row * Ch;
    yr[tid]       = f2bf(d0 * rstd * w[tid]       + b[tid]);
    yr[tid + 256] = f2bf(d1 * rstd * w[tid + 256] + b[tid + 256]);
    yr[tid + 512] = f2bf(d2 * rstd * w[tid + 512] + b[tid + 512]);
}

// ---------------------------------------------------------------- fused mask kernel
__global__ __launch_bounds__(64)
void mask_kernel(const float* __restrict__ mask, float* __restrict__ fg,
                 float* __restrict__ bgw)
{
    int win = blockIdx.x;            // 0..71
    int b = win / 36, w = win % 36;
    int wi = w / 6, wj = w % 6;
    int lane = threadIdx.x;          // 64
    int i = wi * 8 + (lane >> 3), j = wj * 8 + (lane & 7);
    const float* mb = mask + (size_t)b * 192 * 192 + (size_t)(i * 4) * 192 + j * 4;
    float s = 0.0f;
    #pragma unroll
    for (int di = 0; di < 4; ++di) {
        float4 v = *(const float4*)(mb + (size_t)di * 192);
        s += v.x + v.y + v.z + v.w;
    }
    float f = (s * (1.0f / 16.0f) > 0.4f) ? 1.0f : 0.0f;
    fg[b * Lh + i * 48 + j] = f;
    unsigned long long bg = __ballot(f == 0.0f);
    if (lane == 0) bgw[win] = bg ? 1.0f : 0.0f;
}

// ---------------------------------------------------------------- batched weight cast+transpose
__global__ __launch_bounds__(256)
void transpose_all_kernel(const float* __restrict__ w_qkv_g, const float* __restrict__ w_qkv_l,
                          const float* __restrict__ w_o_g, const float* __restrict__ w_o_l,
                          const float* __restrict__ w_fc1, const float* __restrict__ w_fc2,
                          ushort_t* __restrict__ wtq, ushort_t* __restrict__ wt_o_g,
                          ushort_t* __restrict__ wt_o_l, ushort_t* __restrict__ wt_fc1,
                          ushort_t* __restrict__ wt_fc2)
{
    int blk = blockIdx.x;
    const float* W; ushort_t* D; int K, N, nx, bx;
    const size_t CC = (size_t)Ch * Ch;
    if (blk < 432)       { int t = blk / 144; bx = blk % 144;
                           W = w_qkv_g + t * CC; D = wtq + t * CC; K = 768; N = 768; nx = 12; }
    else if (blk < 864)  { int r = blk - 432; int t = r / 144; bx = r % 144;
                           W = w_qkv_l + t * CC; D = wtq + (size_t)2304 * 768 + t * CC;
                           K = 768; N = 768; nx = 12; }
    else if (blk < 1008) { bx = blk - 864;  W = w_o_g; D = wt_o_g; K = 768; N = 768; nx = 12; }
    else if (blk < 1152) { bx = blk - 1008; W = w_o_l; D = wt_o_l; K = 768; N = 768; nx = 12; }
    else if (blk < 1728) { bx = blk - 1152; W = w_fc1; D = wt_fc1; K = 768; N = 3072; nx = 48; }
    else                 { bx = blk - 1728; W = w_fc2; D = wt_fc2; K = 3072; N = 768; nx = 12; }
    int n0 = (bx % nx) * 64;
    int k0 = (bx / nx) * 64;
    int tid = threadIdx.x;
    __shared__ float T[64][65];
    #pragma unroll
    for (int i = 0; i < 16; ++i) {
        int lin = i * 256 + tid;
        int r = lin >> 6, c = lin & 63;
        T[r][c] = W[(size_t)(k0 + r) * N + n0 + c];
    }
    __syncthreads();
    #pragma unroll
    for (int i = 0; i < 16; ++i) {
        int lin = i * 256 + tid;
        int r = lin >> 6, c = lin & 63;
        D[(size_t)(n0 + r) * K + k0 + c] = f2bf(T[c][r]);
    }
}

// ---------------------------------------------------------------- bf16 MFMA GEMM (BM=128, BN template)
// flags: 1=gelu, 2=bf16 out, 4=fg-masked add, 8=bg-local masked add
template<int BNt>
__global__ __launch_bounds__(256)
void gemm_bf16_t(const ushort_t* __restrict__ A, const ushort_t* __restrict__ Bt,
                 const float* __restrict__ bias, const float* __restrict__ residual,
                 void* __restrict__ C, int M, int N, int K, int flags,
                 const float* __restrict__ fg, const float* __restrict__ bgw)
{
    __shared__ ushort_t AsL[128 * 32];
    __shared__ ushort_t BsL[BNt * 32];
    int bm = blockIdx.y * 128;
    int bn = blockIdx.x * BNt;
    int tid = threadIdx.x;
    int lane = tid & 63;
    int wave = tid >> 6;
    int wm = wave >> 1, wn = wave & 1;
    int quad = lane >> 4, l15 = lane & 15;
    constexpr int NJ = BNt / 32;

    int srow = lane >> 2;
    int sg8 = ((lane & 3) ^ ((lane >> 3) & 3)) * 8;
    int fsw = (l15 >> 1) & 3;

    f32x4 acc[4][NJ];
    #pragma unroll
    for (int i = 0; i < 4; ++i)
        #pragma unroll
        for (int j = 0; j < NJ; ++j)
            acc[i][j] = (f32x4){0.f, 0.f, 0.f, 0.f};

    for (int k0 = 0; k0 < K; k0 += 32) {
        __syncthreads();
        llds16(&AsL[wave * 512],
               A + (size_t)(bm + wave * 16 + srow) * K + k0 + sg8);
        llds16(&AsL[(wave + 4) * 512],
               A + (size_t)(bm + (wave + 4) * 16 + srow) * K + k0 + sg8);
        llds16(&BsL[wave * 512],
               Bt + (size_t)(bn + wave * 16 + srow) * K + k0 + sg8);
        if (BNt == 128)
            llds16(&BsL[(wave + 4) * 512],
                   Bt + (size_t)(bn + (wave + 4) * 16 + srow) * K + k0 + sg8);
        __syncthreads();

        bf16x8 af[4], bfr[NJ];
        #pragma unroll
        for (int i = 0; i < 4; ++i)
            af[i] = *(const bf16x8*)&AsL[(wm * 64 + i * 16 + l15) * 32 + ((quad ^ fsw) * 8)];
        #pragma unroll
        for (int j = 0; j < NJ; ++j)
            bfr[j] = *(const bf16x8*)&BsL[(wn * (BNt / 2) + j * 16 + l15) * 32 + ((quad ^ fsw) * 8)];
        #pragma unroll
        for (int i = 0; i < 4; ++i)
            #pragma unroll
            for (int j = 0; j < NJ; ++j)
                acc[i][j] = MFMA16(af[i], bfr[j], acc[i][j]);
    }

    float bia[NJ];
    #pragma unroll
    for (int j = 0; j < NJ; ++j) bia[j] = bias[bn + wn * (BNt / 2) + j * 16 + l15];

    #pragma unroll
    for (int i = 0; i < 4; ++i) {
        #pragma unroll
        for (int r = 0; r < 4; ++r) {
            int row = bm + wm * 64 + i * 16 + quad * 4 + r;
            float keep = 1.0f;
            if (flags & 4) keep = (fg[row] != 0.0f) ? 1.0f : 0.0f;
            if (flags & 8) {
                int bb = (row >= Lh) ? 1 : 0;
                int n = row - bb * Lh;
                int ii = n / 48, jj = n % 48;
                keep = (fg[row] == 0.0f && bgw[bb * 36 + (ii >> 3) * 6 + (jj >> 3)] != 0.0f)
                           ? 1.0f : 0.0f;
            }
            #pragma unroll
            for (int j = 0; j < NJ; ++j) {
                int col = bn + wn * (BNt / 2) + j * 16 + l15;
                float v = acc[i][j][r] + bia[j];
                if (flags & 1) v = v * 0.5f * (1.0f + erff(v * 0.70710678f));
                float o;
                if (flags & (4 | 8)) o = residual[(size_t)row * N + col] + keep * v;
                else if (residual)   o = residual[(size_t)row * N + col] + v;
                else                 o = v;
                if (flags & 2) ((ushort_t*)C)[(size_t)row * N + col] = f2bf(o);
                else           ((float*)C)[(size_t)row * N + col] = o;
            }
        }
    }
}

// ---------------------------------------------------------------- fused attention (global split-K + local)
// Global: 128-q tile, K-tiles split in 2 halves of 18 across separate blocks
// (no-max softmax -> partials are additive: og=sum exp*V, lg=sum exp, fp32).
// Local: 64-q window, 1 key tile, bf16 out with divide.
// Vt XOR-swizzled: Vt[d][tok ^ ((d>>3)<<3)] -> conflict-free transposed staging.

__device__ __forceinline__ void attn_global_body(
    const ushort_t* __restrict__ QKV, const float* __restrict__ fg,
    float* __restrict__ og, float* __restrict__ lg,
    int tile, int h, int b, int kt0,
    ushort_t (*Ks)[72], ushort_t (*Vt)[72], ushort_t (*Ps)[72], float* fgs)
{
    int tid = threadIdx.x;
    int lane = tid & 63;
    int wave = tid >> 6;
    int quad = lane >> 4, l15 = lane & 15;

    bf16x8 aq[2][2];
    #pragma unroll
    for (int s = 0; s < 2; ++s) {
        int ql = wave * 32 + s * 16 + l15;
        int tok = tile * 128 + ql;
        const ushort_t* qbase = QKV + (size_t)(b * Lh + tok) * QS + h * 64;
        #pragma unroll
        for (int step = 0; step < 2; ++step)
            aq[s][step] = *(const bf16x8*)(qbase + step * 32 + quad * 8);
    }

    float l_part[2][4];
    f32x4 o_acc[2][4];
    #pragma unroll
    for (int s = 0; s < 2; ++s)
        #pragma unroll
        for (int t4 = 0; t4 < 4; ++t4) {
            o_acc[s][t4] = (f32x4){0.f, 0.f, 0.f, 0.f};
            l_part[s][t4] = 0.f;
        }

    // prefetch tile kt0
    uint4 kx[2], vx[2];
    #pragma unroll
    for (int it = 0; it < 2; ++it) {
        int e = tid + it * 256;
        int row = e >> 3, g = e & 7;
        int tok = kt0 * 64 + row;
        const ushort_t* base = QKV + (size_t)(b * Lh + tok) * QS + h * 64 + g * 8;
        kx[it] = *(const uint4*)(base + 768);
        vx[it] = *(const uint4*)(base + 1536);
    }
    float fgn = 0.f;
    if (tid < 64) fgn = fg[b * Lh + kt0 * 64 + tid];

    for (int kt = 0; kt < 18; ++kt) {
        __syncthreads();
        #pragma unroll
        for (int it = 0; it < 2; ++it) {
            int e = tid + it * 256;
            int row = e >> 3, g = e & 7;
            *(uint4*)&Ks[row][g * 8] = kx[it];
            union { uint4 raw; ushort_t us[8]; } vv;
            vv.raw = vx[it];
            int col = row ^ (g << 3);
            #pragma unroll
            for (int j = 0; j < 8; ++j) Vt[g * 8 + j][col] = vv.us[j];
        }
        if (tid < 64) fgs[tid] = (fgn - 1.0f) * 1e9f;
        __syncthreads();

        if (kt + 1 < 18) {
            #pragma unroll
            for (int it = 0; it < 2; ++it) {
                int e = tid + it * 256;
                int row = e >> 3, g = e & 7;
                int tok = (kt0 + kt + 1) * 64 + row;
                const ushort_t* base = QKV + (size_t)(b * Lh + tok) * QS + h * 64 + g * 8;
                kx[it] = *(const uint4*)(base + 768);
                vx[it] = *(const uint4*)(base + 1536);
            }
            if (tid < 64) fgn = fg[b * Lh + (kt0 + kt + 1) * 64 + tid];
        }

        f32x4 s4[2][4];
        #pragma unroll
        for (int s = 0; s < 2; ++s)
            #pragma unroll
            for (int j4 = 0; j4 < 4; ++j4) s4[s][j4] = (f32x4){0.f, 0.f, 0.f, 0.f};
        #pragma unroll
        for (int step = 0; step < 2; ++step) {
            bf16x8 bk[4];
            #pragma unroll
            for (int j4 = 0; j4 < 4; ++j4)
                bk[j4] = *(const bf16x8*)&Ks[j4 * 16 + l15][step * 32 + quad * 8];
            #pragma unroll
            for (int s = 0; s < 2; ++s)
                #pragma unroll
                for (int j4 = 0; j4 < 4; ++j4)
                    s4[s][j4] = MFMA16(aq[s][step], bk[j4], s4[s][j4]);
        }
        #pragma unroll
        for (int s = 0; s < 2; ++s) {
            int p0 = wave * 32 + s * 16;
            #pragma unroll
            for (int j4 = 0; j4 < 4; ++j4) {
                float mb = fgs[j4 * 16 + l15];
                #pragma unroll
                for (int r = 0; r < 4; ++r) {
                    float p = __expf(s4[s][j4][r] * 0.125f + mb);
                    l_part[s][r] += p;
                    Ps[p0 + quad * 4 + r][j4 * 16 + l15] = f2bf(p);
                }
            }
        }
        #pragma unroll
        for (int step = 0; step < 2; ++step) {
            bf16x8 bv[4];
            #pragma unroll
            for (int t4 = 0; t4 < 4; ++t4) {
                int dd = t4 * 16 + l15;
                int cb = ((step * 4 + quad) ^ ((dd >> 3) & 7)) * 8;
                bv[t4] = *(const bf16x8*)&Vt[dd][cb];
            }
            #pragma unroll
            for (int s = 0; s < 2; ++s) {
                int p0 = wave * 32 + s * 16;
                bf16x8 a = *(const bf16x8*)&Ps[p0 + l15][step * 32 + quad * 8];
                #pragma unroll
                for (int t4 = 0; t4 < 4; ++t4)
                    o_acc[s][t4] = MFMA16(a, bv[t4], o_acc[s][t4]);
            }
        }
    }

    // fp32 partial epilogue (no divide)
    #pragma unroll
    for (int s = 0; s < 2; ++s) {
        #pragma unroll
        for (int r = 0; r < 4; ++r) {
            float v = l_part[s][r];
            #pragma unroll
            for (int off = 8; off >= 1; off >>= 1)
                v += __shfl_xor(v, off, 64);
            int ql = wave * 32 + s * 16 + quad * 4 + r;
            int tok = tile * 128 + ql;
            if (l15 == 0) lg[(b * NHh + h) * Lh + tok] = v;
            #pragma unroll
            for (int t4 = 0; t4 < 4; ++t4)
                og[(size_t)(b * Lh + tok) * Ch + h * 64 + t4 * 16 + l15] = o_acc[s][t4][r];
        }
    }
}

__device__ __forceinline__ void attn_local_body(
    const ushort_t* __restrict__ QKV, ushort_t* __restrict__ O,
    int tile, int h, int b,
    ushort_t (*Ks)[72], ushort_t (*Vt)[72], ushort_t (*Ps)[72])
{
    int tid = threadIdx.x;
    int lane = tid & 63;
    int wave = tid >> 6;
    int quad = lane >> 4, l15 = lane & 15;
    int wi = tile / 6, wj = tile % 6;

    bf16x8 aq[2];
    {
        int ql = wave * 16 + l15;
        int tok = (wi * 8 + (ql >> 3)) * 48 + wj * 8 + (ql & 7);
        const ushort_t* qbase = QKV + (size_t)(b * Lh + tok) * QS + 2304 + h * 64;
        #pragma unroll
        for (int step = 0; step < 2; ++step)
            aq[step] = *(const bf16x8*)(qbase + step * 32 + quad * 8);
    }

    float l_part[4] = {0.f, 0.f, 0.f, 0.f};
    f32x4 o_acc[4];
    #pragma unroll
    for (int t4 = 0; t4 < 4; ++t4) o_acc[t4] = (f32x4){0.f, 0.f, 0.f, 0.f};

    #pragma unroll
    for (int it = 0; it < 2; ++it) {
        int e = tid + it * 256;
        int row = e >> 3, g = e & 7;
        int tok = (wi * 8 + (row >> 3)) * 48 + wj * 8 + (row & 7);
        const ushort_t* base = QKV + (size_t)(b * Lh + tok) * QS + 2304 + h * 64 + g * 8;
        uint4 kvv = *(const uint4*)(base + 768);
        *(uint4*)&Ks[row][g * 8] = kvv;
        union { uint4 raw; ushort_t us[8]; } vv;
        vv.raw = *(const uint4*)(base + 1536);
        int col = row ^ (g << 3);
        #pragma unroll
        for (int j = 0; j < 8; ++j) Vt[g * 8 + j][col] = vv.us[j];
    }
    __syncthreads();

    f32x4 s4[4];
    #pragma unroll
    for (int j4 = 0; j4 < 4; ++j4) s4[j4] = (f32x4){0.f, 0.f, 0.f, 0.f};
    #pragma unroll
    for (int step = 0; step < 2; ++step) {
        bf16x8 bk[4];
        #pragma unroll
        for (int j4 = 0; j4 < 4; ++j4)
            bk[j4] = *(const bf16x8*)&Ks[j4 * 16 + l15][step * 32 + quad * 8];
        #pragma unroll
        for (int j4 = 0; j4 < 4; ++j4)
            s4[j4] = MFMA16(aq[step], bk[j4], s4[j4]);
    }
    int p0 = wave * 16;
    #pragma unroll
    for (int j4 = 0; j4 < 4; ++j4)
        #pragma unroll
        for (int r = 0; r < 4; ++r) {
            float p = __expf(s4[j4][r] * 0.125f);
            l_part[r] += p;
            Ps[p0 + quad * 4 + r][j4 * 16 + l15] = f2bf(p);
        }
    #pragma unroll
    for (int step = 0; step < 2; ++step) {
        bf16x8 bv[4];
        #pragma unroll
        for (int t4 = 0; t4 < 4; ++t4) {
            int dd = t4 * 16 + l15;
            int cb = ((step * 4 + quad) ^ ((dd >> 3) & 7)) * 8;
            bv[t4] = *(const bf16x8*)&Vt[dd][cb];
        }
        bf16x8 a = *(const bf16x8*)&Ps[p0 + l15][step * 32 + quad * 8];
        #pragma unroll
        for (int t4 = 0; t4 < 4; ++t4)
            o_acc[t4] = MFMA16(a, bv[t4], o_acc[t4]);
    }

    #pragma unroll
    for (int r = 0; r < 4; ++r) {
        float v = l_part[r];
        #pragma unroll
        for (int off = 8; off >= 1; off >>= 1)
            v += __shfl_xor(v, off, 64);
        float inv = 1.0f / v;
        int ql = wave * 16 + quad * 4 + r;
        int tok = (wi * 8 + (ql >> 3)) * 48 + wj * 8 + (ql & 7);
        #pragma unroll
        for (int t4 = 0; t4 < 4; ++t4)
            O[(size_t)(b * Lh + tok) * Ch + h * 64 + t4 * 16 + l15] =
                f2bf(o_acc[t4][r] * inv);
    }
}

__global__ __launch_bounds__(256)
void attn_fused_kernel(const ushort_t* __restrict__ QKV, const float* __restrict__ fg,
                       float* __restrict__ og, float* __restrict__ lg,
                       ushort_t* __restrict__ ctxl)
{
    __shared__ ushort_t Ks[64][72];
    __shared__ ushort_t Vt[64][72];
    __shared__ ushort_t Ps[128][72];
    __shared__ float fgs[64];

    int gid = blockIdx.x;
    if (gid < 864) {
        int kh = gid & 1;
        int rr = gid >> 1;                      // 0..431
        int tile = rr % 18;
        int h = (rr / 18) % NHh;
        int b = rr / (18 * NHh);
        const size_t U = (size_t)Bh * Lh * Ch;
        attn_global_body(QKV, fg, og + (size_t)kh * U, lg + kh * (Bh * NHh * Lh),
                         tile, h, b, kh * 18, Ks, Vt, Ps, fgs);
    } else {
        int rr = gid - 864;                     // 0..863
        int tile = rr % 36;
        int h = (rr / 36) % NHh;
        int b = rr / (36 * NHh);
        attn_local_body(QKV, ctxl, tile, h, b, Ks, Vt, Ps);
    }
}

// ---------------------------------------------------------------- split-K combine: ctx = (o0+o1)/(l0+l1), bf16
__global__ __launch_bounds__(256)
void attn_combine_kernel(const float* __restrict__ og, const float* __restrict__ lg,
                         ushort_t* __restrict__ ctx)
{
    const size_t U = (size_t)Bh * Lh * Ch;
    int idx = blockIdx.x * 256 + threadIdx.x;       // float4 index; U/4 = 884736 exact
    size_t f = (size_t)idx * 4;
    int tg = (int)(f / Ch);                          // b*Lh + q
    int c = (int)(f % Ch);
    int h = c >> 6;
    int b = tg / Lh, q = tg % Lh;
    float l = lg[(b * NHh + h) * Lh + q] + lg[Bh * NHh * Lh + (b * NHh + h) * Lh + q];
    float inv = 1.0f / l;
    float4 a = ((const float4*)og)[idx];
    float4 bb = ((const float4*)(og + U))[idx];
    uint_t p0 = ((uint_t)f2bf((a.y + bb.y) * inv) << 16) | f2bf((a.x + bb.x) * inv);
    uint_t p1 = ((uint_t)f2bf((a.w + bb.w) * inv) << 16) | f2bf((a.z + bb.z) * inv);
    ((uint2*)ctx)[idx] = make_uint2(p0, p1);
}

// ---------------------------------------------------------------- launch
extern "C" void kernel_launch(void* const* d_in, const int* in_sizes, int n_in,
                              void* d_out, int out_size, void* d_ws, size_t ws_size,
                              hipStream_t stream)
{
    const float* x       = (const float*)d_in[0];
    const float* mask    = (const float*)d_in[1];
    const float* w_qkv_g = (const float*)d_in[2];
    const float* b_qkv_g = (const float*)d_in[3];
    const float* w_o_g   = (const float*)d_in[4];
    const float* b_o_g   = (const float*)d_in[5];
    const float* w_qkv_l = (const float*)d_in[6];
    const float* b_qkv_l = (const float*)d_in[7];
    const float* w_o_l   = (const float*)d_in[8];
    const float* b_o_l   = (const float*)d_in[9];
    const float* ln1_w   = (const float*)d_in[10];
    const float* ln1_b   = (const float*)d_in[11];
    const float* ln2_w   = (const float*)d_in[12];
    const float* ln2_b   = (const float*)d_in[13];
    const float* w_fc1   = (const float*)d_in[14];
    const float* b_fc1   = (const float*)d_in[15];
    const float* w_fc2   = (const float*)d_in[16];
    const float* b_fc2   = (const float*)d_in[17];
    float* out = (float*)d_out;

    const size_t U = (size_t)Bh * Lh * Ch;           // 3,538,944
    char* p = (char*)d_ws;
    ushort_t* qkvb = (ushort_t*)p;        p += (size_t)4608 * 4608 * 2;  // [4608][4608] bf16
    ushort_t* midb = qkvb;                                               // [4608][3072] aliases
    ushort_t* ctxg = (ushort_t*)p;        p += U * 2;
    ushort_t* ctxl = (ushort_t*)p;        p += U * 2;
    ushort_t* xnb  = (ushort_t*)p;        p += U * 2;
    float*    x1   = (float*)p;           p += U * 4;
    float*    og   = (float*)p;           p += 2 * U * 4;                // split-K fp32 partials
    float*    lg   = (float*)p;           p += 2 * (size_t)Bh * NHh * Lh * 4;
    ushort_t* wtq  = (ushort_t*)p;        p += (size_t)4608 * 768 * 2;   // qkv g|l concat
    ushort_t* wt_o_g = (ushort_t*)p;      p += (size_t)768 * 768 * 2;
    ushort_t* wt_o_l = (ushort_t*)p;      p += (size_t)768 * 768 * 2;
    ushort_t* wt_fc1 = (ushort_t*)p;      p += (size_t)3072 * 768 * 2;
    ushort_t* wt_fc2 = (ushort_t*)p;      p += (size_t)768 * 3072 * 2;
    float*    biasq  = (float*)p;         p += 4608 * 4;
    float*    fg     = (float*)p;         p += Bh * Lh * 4;
    float*    bgw    = (float*)p;

    const int Mrows = Bh * Lh;                   // 4608
    dim3 blk(256);

    // concat qkv biases (g then l)
    hipMemcpyAsync(biasq, b_qkv_g, 2304 * sizeof(float), hipMemcpyDeviceToDevice, stream);
    hipMemcpyAsync(biasq + 2304, b_qkv_l, 2304 * sizeof(float), hipMemcpyDeviceToDevice, stream);

    // all weight transposes in one dispatch
    transpose_all_kernel<<<2304, blk, 0, stream>>>(
        w_qkv_g, w_qkv_l, w_o_g, w_o_l, w_fc1, w_fc2,
        wtq, wt_o_g, wt_o_l, wt_fc1, wt_fc2);

    // LN1 -> bf16; fused masks
    layernorm_bf16_kernel<<<Mrows, blk, 0, stream>>>(x, ln1_w, ln1_b, xnb);
    mask_kernel<<<72, dim3(64), 0, stream>>>(mask, fg, bgw);

    // fused QKV GEMM for both branches (N=4608)
    gemm_bf16_t<128><<<dim3(4608 / 128, Mrows / 128), blk, 0, stream>>>(
        xnb, wtq, biasq, nullptr, qkvb, Mrows, 4608, Ch, 2, nullptr, nullptr);

    // fused attention: 864 global split-K blocks + 864 local blocks
    attn_fused_kernel<<<1728, blk, 0, stream>>>(qkvb, fg, og, lg, ctxl);
    attn_combine_kernel<<<(int)(U / 4 / 256), blk, 0, stream>>>(og, lg, ctxg);

    // masked o-projections into x1
    gemm_bf16_t<64><<<dim3(Ch / 64, Mrows / 128), blk, 0, stream>>>(
        ctxg, wt_o_g, b_o_g, x, x1, Mrows, Ch, Ch, 4, fg, nullptr);
    gemm_bf16_t<64><<<dim3(Ch / 64, Mrows / 128), blk, 0, stream>>>(
        ctxl, wt_o_l, b_o_l, x1, x1, Mrows, Ch, Ch, 8, fg, bgw);

    // LN2 -> bf16
    layernorm_bf16_kernel<<<Mrows, blk, 0, stream>>>(x1, ln2_w, ln2_b, xnb);

    // MLP
    gemm_bf16_t<128><<<dim3(3072 / 128, Mrows / 128), blk, 0, stream>>>(
        xnb, wt_fc1, b_fc1, nullptr, midb, Mrows, 3072, Ch, 1 | 2, nullptr, nullptr);
    gemm_bf16_t<64><<<dim3(Ch / 64, Mrows / 128), blk, 0, stream>>>(
        midb, wt_fc2, b_fc2, x1, out, Mrows, Ch, 3072, 0, nullptr, nullptr);
}

// Round 9
// 493.415 us; speedup vs baseline: 1.0292x; 1.0292x over previous
//
#include <hip/hip_runtime.h>
#include <math.h>

#define Lh 2304
#define Ch 768
#define NHh 12
#define Bh 2
#define QS 4608   // row stride of fused qkv activation buffer (global q|k|v, local q|k|v)

typedef unsigned short ushort_t;
typedef unsigned int uint_t;
typedef __attribute__((ext_vector_type(8))) short bf16x8;
typedef __attribute__((ext_vector_type(4))) float f32x4;
#define MFMA16(a, b, c) __builtin_amdgcn_mfma_f32_16x16x32_bf16(a, b, c, 0, 0, 0)

__device__ __forceinline__ ushort_t f2bf(float f) {
    union { float f; uint_t u; } v; v.f = f;
    uint_t u = v.u + 0x7fffu + ((v.u >> 16) & 1u);   // RNE
    return (ushort_t)(u >> 16);
}

// async global->LDS, 16B/lane, dest = wave-uniform base + lane*16
__device__ __forceinline__ void llds16(ushort_t* dst, const ushort_t* src) {
    __builtin_amdgcn_global_load_lds(
        (__attribute__((address_space(1))) void*)(const_cast<ushort_t*>(src)),
        (__attribute__((address_space(3))) void*)dst, 16, 0, 0);
}

// ---------------------------------------------------------------- layernorm (fp32 in, bf16 out)
__global__ __launch_bounds__(256)
void layernorm_bf16_kernel(const float* __restrict__ x, const float* __restrict__ w,
                           const float* __restrict__ b, ushort_t* __restrict__ y)
{
    int row = blockIdx.x;
    int tid = threadIdx.x;
    const float* xr = x + (size_t)row * Ch;
    float v0 = xr[tid], v1 = xr[tid + 256], v2 = xr[tid + 512];
    __shared__ float red[256];
    red[tid] = v0 + v1 + v2;
    __syncthreads();
    for (int st = 128; st > 0; st >>= 1) {
        if (tid < st) red[tid] += red[tid + st];
        __syncthreads();
    }
    float mean = red[0] * (1.0f / 768.0f);
    __syncthreads();
    float d0 = v0 - mean, d1 = v1 - mean, d2 = v2 - mean;
    red[tid] = d0 * d0 + d1 * d1 + d2 * d2;
    __syncthreads();
    for (int st = 128; st > 0; st >>= 1) {
        if (tid < st) red[tid] += red[tid + st];
        __syncthreads();
    }
    float rstd = rsqrtf(red[0] * (1.0f / 768.0f) + 1e-6f);
    ushort_t* yr = y + (size_t)row * Ch;
    yr[tid]       = f2bf(d0 * rstd * w[tid]       + b[tid]);
    yr[tid + 256] = f2bf(d1 * rstd * w[tid + 256] + b[tid + 256]);
    yr[tid + 512] = f2bf(d2 * rstd * w[tid + 512] + b[tid + 512]);
}

// ---------------------------------------------------------------- fused mask kernel
__global__ __launch_bounds__(64)
void mask_kernel(const float* __restrict__ mask, float* __restrict__ fg,
                 float* __restrict__ bgw)
{
    int win = blockIdx.x;            // 0..71
    int b = win / 36, w = win % 36;
    int wi = w / 6, wj = w % 6;
    int lane = threadIdx.x;          // 64
    int i = wi * 8 + (lane >> 3), j = wj * 8 + (lane & 7);
    const float* mb = mask + (size_t)b * 192 * 192 + (size_t)(i * 4) * 192 + j * 4;
    float s = 0.0f;
    #pragma unroll
    for (int di = 0; di < 4; ++di) {
        float4 v = *(const float4*)(mb + (size_t)di * 192);
        s += v.x + v.y + v.z + v.w;
    }
    float f = (s * (1.0f / 16.0f) > 0.4f) ? 1.0f : 0.0f;
    fg[b * Lh + i * 48 + j] = f;
    unsigned long long bg = __ballot(f == 0.0f);
    if (lane == 0) bgw[win] = bg ? 1.0f : 0.0f;
}

// ---------------------------------------------------------------- batched weight cast+transpose
__global__ __launch_bounds__(256)
void transpose_all_kernel(const float* __restrict__ w_qkv_g, const float* __restrict__ w_qkv_l,
                          const float* __restrict__ w_o_g, const float* __restrict__ w_o_l,
                          const float* __restrict__ w_fc1, const float* __restrict__ w_fc2,
                          ushort_t* __restrict__ wtq, ushort_t* __restrict__ wt_o_g,
                          ushort_t* __restrict__ wt_o_l, ushort_t* __restrict__ wt_fc1,
                          ushort_t* __restrict__ wt_fc2)
{
    int blk = blockIdx.x;
    const float* W; ushort_t* D; int K, N, nx, bx;
    const size_t CC = (size_t)Ch * Ch;
    if (blk < 432)       { int t = blk / 144; bx = blk % 144;
                           W = w_qkv_g + t * CC; D = wtq + t * CC; K = 768; N = 768; nx = 12; }
    else if (blk < 864)  { int r = blk - 432; int t = r / 144; bx = r % 144;
                           W = w_qkv_l + t * CC; D = wtq + (size_t)2304 * 768 + t * CC;
                           K = 768; N = 768; nx = 12; }
    else if (blk < 1008) { bx = blk - 864;  W = w_o_g; D = wt_o_g; K = 768; N = 768; nx = 12; }
    else if (blk < 1152) { bx = blk - 1008; W = w_o_l; D = wt_o_l; K = 768; N = 768; nx = 12; }
    else if (blk < 1728) { bx = blk - 1152; W = w_fc1; D = wt_fc1; K = 768; N = 3072; nx = 48; }
    else                 { bx = blk - 1728; W = w_fc2; D = wt_fc2; K = 3072; N = 768; nx = 12; }
    int n0 = (bx % nx) * 64;
    int k0 = (bx / nx) * 64;
    int tid = threadIdx.x;
    __shared__ float T[64][65];
    #pragma unroll
    for (int i = 0; i < 16; ++i) {
        int lin = i * 256 + tid;
        int r = lin >> 6, c = lin & 63;
        T[r][c] = W[(size_t)(k0 + r) * N + n0 + c];
    }
    __syncthreads();
    #pragma unroll
    for (int i = 0; i < 16; ++i) {
        int lin = i * 256 + tid;
        int r = lin >> 6, c = lin & 63;
        D[(size_t)(n0 + r) * K + k0 + c] = f2bf(T[c][r]);
    }
}

// ---------------------------------------------------------------- bf16 MFMA GEMM (BM=128, BN template)
// flags: 1=gelu, 2=bf16 out, 4=fg-masked add, 8=bg-local masked add
template<int BNt>
__global__ __launch_bounds__(256)
void gemm_bf16_t(const ushort_t* __restrict__ A, const ushort_t* __restrict__ Bt,
                 const float* __restrict__ bias, const float* __restrict__ residual,
                 void* __restrict__ C, int M, int N, int K, int flags,
                 const float* __restrict__ fg, const float* __restrict__ bgw)
{
    __shared__ ushort_t AsL[128 * 32];
    __shared__ ushort_t BsL[BNt * 32];
    int bm = blockIdx.y * 128;
    int bn = blockIdx.x * BNt;
    int tid = threadIdx.x;
    int lane = tid & 63;
    int wave = tid >> 6;
    int wm = wave >> 1, wn = wave & 1;
    int quad = lane >> 4, l15 = lane & 15;
    constexpr int NJ = BNt / 32;

    int srow = lane >> 2;
    int sg8 = ((lane & 3) ^ ((lane >> 3) & 3)) * 8;
    int fsw = (l15 >> 1) & 3;

    f32x4 acc[4][NJ];
    #pragma unroll
    for (int i = 0; i < 4; ++i)
        #pragma unroll
        for (int j = 0; j < NJ; ++j)
            acc[i][j] = (f32x4){0.f, 0.f, 0.f, 0.f};

    for (int k0 = 0; k0 < K; k0 += 32) {
        __syncthreads();
        llds16(&AsL[wave * 512],
               A + (size_t)(bm + wave * 16 + srow) * K + k0 + sg8);
        llds16(&AsL[(wave + 4) * 512],
               A + (size_t)(bm + (wave + 4) * 16 + srow) * K + k0 + sg8);
        llds16(&BsL[wave * 512],
               Bt + (size_t)(bn + wave * 16 + srow) * K + k0 + sg8);
        if (BNt == 128)
            llds16(&BsL[(wave + 4) * 512],
                   Bt + (size_t)(bn + (wave + 4) * 16 + srow) * K + k0 + sg8);
        __syncthreads();

        bf16x8 af[4], bfr[NJ];
        #pragma unroll
        for (int i = 0; i < 4; ++i)
            af[i] = *(const bf16x8*)&AsL[(wm * 64 + i * 16 + l15) * 32 + ((quad ^ fsw) * 8)];
        #pragma unroll
        for (int j = 0; j < NJ; ++j)
            bfr[j] = *(const bf16x8*)&BsL[(wn * (BNt / 2) + j * 16 + l15) * 32 + ((quad ^ fsw) * 8)];
        #pragma unroll
        for (int i = 0; i < 4; ++i)
            #pragma unroll
            for (int j = 0; j < NJ; ++j)
                acc[i][j] = MFMA16(af[i], bfr[j], acc[i][j]);
    }

    float bia[NJ];
    #pragma unroll
    for (int j = 0; j < NJ; ++j) bia[j] = bias[bn + wn * (BNt / 2) + j * 16 + l15];

    #pragma unroll
    for (int i = 0; i < 4; ++i) {
        #pragma unroll
        for (int r = 0; r < 4; ++r) {
            int row = bm + wm * 64 + i * 16 + quad * 4 + r;
            float keep = 1.0f;
            if (flags & 4) keep = (fg[row] != 0.0f) ? 1.0f : 0.0f;
            if (flags & 8) {
                int bb = (row >= Lh) ? 1 : 0;
                int n = row - bb * Lh;
                int ii = n / 48, jj = n % 48;
                keep = (fg[row] == 0.0f && bgw[bb * 36 + (ii >> 3) * 6 + (jj >> 3)] != 0.0f)
                           ? 1.0f : 0.0f;
            }
            #pragma unroll
            for (int j = 0; j < NJ; ++j) {
                int col = bn + wn * (BNt / 2) + j * 16 + l15;
                float v = acc[i][j][r] + bia[j];
                if (flags & 1) v = v * 0.5f * (1.0f + erff(v * 0.70710678f));
                float o;
                if (flags & (4 | 8)) o = residual[(size_t)row * N + col] + keep * v;
                else if (residual)   o = residual[(size_t)row * N + col] + v;
                else                 o = v;
                if (flags & 2) ((ushort_t*)C)[(size_t)row * N + col] = f2bf(o);
                else           ((float*)C)[(size_t)row * N + col] = o;
            }
        }
    }
}

// ---------------------------------------------------------------- fused attention (global + local)
// S^T trick: S-MFMA args swapped (A=K-frag, B=Q-frag) -> C-layout gives each lane
// 4 CONSECUTIVE k for one q -> P stored with ds_write_b64 (4x fewer LDS insts),
// truncating bf16 pack via v_perm (P in (0,1], trunc error cancels in division).
// l lives per-lane (q = l15); 2-shuffle quad reduce; broadcast via lbuf.
// Vt XOR-swizzled: Vt[d][tok ^ ((d>>3)<<3)] -> conflict-free transposed staging.

__device__ __forceinline__ void attn_global_body(
    const ushort_t* __restrict__ QKV, const float* __restrict__ fg,
    ushort_t* __restrict__ O, int tile, int h, int b,
    ushort_t (*Ks)[72], ushort_t (*Vt)[72], ushort_t (*Ps)[72],
    float* fgs, float* lbuf)
{
    int tid = threadIdx.x;
    int lane = tid & 63;
    int wave = tid >> 6;
    int quad = lane >> 4, l15 = lane & 15;

    // Q fragments (serve as MFMA B-operand: lane l15 = q, 8 consecutive d)
    bf16x8 aq[2][2];
    #pragma unroll
    for (int s = 0; s < 2; ++s) {
        int ql = wave * 32 + s * 16 + l15;
        int tok = tile * 128 + ql;
        const ushort_t* qbase = QKV + (size_t)(b * Lh + tok) * QS + h * 64;
        #pragma unroll
        for (int step = 0; step < 2; ++step)
            aq[s][step] = *(const bf16x8*)(qbase + step * 32 + quad * 8);
    }

    float l_part[2] = {0.f, 0.f};
    f32x4 o_acc[2][4];
    #pragma unroll
    for (int s = 0; s < 2; ++s)
        #pragma unroll
        for (int t4 = 0; t4 < 4; ++t4) o_acc[s][t4] = (f32x4){0.f, 0.f, 0.f, 0.f};

    // prefetch tile 0
    uint4 kx[2], vx[2];
    #pragma unroll
    for (int it = 0; it < 2; ++it) {
        int e = tid + it * 256;
        int row = e >> 3, g = e & 7;
        const ushort_t* base = QKV + (size_t)(b * Lh + row) * QS + h * 64 + g * 8;
        kx[it] = *(const uint4*)(base + 768);
        vx[it] = *(const uint4*)(base + 1536);
    }
    float fgn = 0.f;
    if (tid < 64) fgn = fg[b * Lh + tid];

    for (int kt = 0; kt < 36; ++kt) {
        __syncthreads();
        #pragma unroll
        for (int it = 0; it < 2; ++it) {
            int e = tid + it * 256;
            int row = e >> 3, g = e & 7;
            *(uint4*)&Ks[row][g * 8] = kx[it];
            union { uint4 raw; ushort_t us[8]; } vv;
            vv.raw = vx[it];
            int col = row ^ (g << 3);
            #pragma unroll
            for (int j = 0; j < 8; ++j) Vt[g * 8 + j][col] = vv.us[j];
        }
        if (tid < 64) fgs[tid] = (fgn - 1.0f) * 1e9f;
        __syncthreads();

        if (kt + 1 < 36) {
            #pragma unroll
            for (int it = 0; it < 2; ++it) {
                int e = tid + it * 256;
                int row = e >> 3, g = e & 7;
                int tok = (kt + 1) * 64 + row;
                const ushort_t* base = QKV + (size_t)(b * Lh + tok) * QS + h * 64 + g * 8;
                kx[it] = *(const uint4*)(base + 768);
                vx[it] = *(const uint4*)(base + 1536);
            }
            if (tid < 64) fgn = fg[b * Lh + (kt + 1) * 64 + tid];
        }

        // S^T = K Q^T: per (s,j4) lane holds S[q=p0+l15][k=j4*16+quad*4+r]
        f32x4 s4[2][4];
        #pragma unroll
        for (int s = 0; s < 2; ++s)
            #pragma unroll
            for (int j4 = 0; j4 < 4; ++j4) s4[s][j4] = (f32x4){0.f, 0.f, 0.f, 0.f};
        #pragma unroll
        for (int step = 0; step < 2; ++step) {
            bf16x8 bk[4];
            #pragma unroll
            for (int j4 = 0; j4 < 4; ++j4)
                bk[j4] = *(const bf16x8*)&Ks[j4 * 16 + l15][step * 32 + quad * 8];
            #pragma unroll
            for (int s = 0; s < 2; ++s)
                #pragma unroll
                for (int j4 = 0; j4 < 4; ++j4)
                    s4[s][j4] = MFMA16(bk[j4], aq[s][step], s4[s][j4]);
        }
        // exp + mask; pack 4 consecutive k as 2x b32 (truncating) -> one b64 write
        #pragma unroll
        for (int s = 0; s < 2; ++s) {
            int p0 = wave * 32 + s * 16;
            #pragma unroll
            for (int j4 = 0; j4 < 4; ++j4) {
                float4 mb4 = *(const float4*)&fgs[j4 * 16 + quad * 4];
                float e0 = __expf(s4[s][j4][0] * 0.125f + mb4.x);
                float e1 = __expf(s4[s][j4][1] * 0.125f + mb4.y);
                float e2 = __expf(s4[s][j4][2] * 0.125f + mb4.z);
                float e3 = __expf(s4[s][j4][3] * 0.125f + mb4.w);
                l_part[s] += (e0 + e1) + (e2 + e3);
                uint_t a01 = __builtin_amdgcn_perm(__float_as_uint(e1), __float_as_uint(e0), 0x07060302u);
                uint_t a23 = __builtin_amdgcn_perm(__float_as_uint(e3), __float_as_uint(e2), 0x07060302u);
                *(uint2*)&Ps[p0 + l15][j4 * 16 + quad * 4] = make_uint2(a01, a23);
            }
        }
        // PV
        #pragma unroll
        for (int step = 0; step < 2; ++step) {
            bf16x8 bv[4];
            #pragma unroll
            for (int t4 = 0; t4 < 4; ++t4) {
                int dd = t4 * 16 + l15;
                int cb = ((step * 4 + quad) ^ ((dd >> 3) & 7)) * 8;
                bv[t4] = *(const bf16x8*)&Vt[dd][cb];
            }
            #pragma unroll
            for (int s = 0; s < 2; ++s) {
                int p0 = wave * 32 + s * 16;
                bf16x8 a = *(const bf16x8*)&Ps[p0 + l15][step * 32 + quad * 8];
                #pragma unroll
                for (int t4 = 0; t4 < 4; ++t4)
                    o_acc[s][t4] = MFMA16(a, bv[t4], o_acc[s][t4]);
            }
        }
    }

    // l: reduce across quads (k-groups), broadcast via lbuf
    #pragma unroll
    for (int s = 0; s < 2; ++s) {
        float v = l_part[s];
        v += __shfl_xor(v, 16, 64);
        v += __shfl_xor(v, 32, 64);
        if (quad == 0) lbuf[wave * 32 + s * 16 + l15] = v;
    }
    // epilogue
    #pragma unroll
    for (int s = 0; s < 2; ++s) {
        #pragma unroll
        for (int r = 0; r < 4; ++r) {
            int ql = wave * 32 + s * 16 + quad * 4 + r;
            float inv = 1.0f / lbuf[ql];
            int tok = tile * 128 + ql;
            #pragma unroll
            for (int t4 = 0; t4 < 4; ++t4)
                O[(size_t)(b * Lh + tok) * Ch + h * 64 + t4 * 16 + l15] =
                    f2bf(o_acc[s][t4][r] * inv);
        }
    }
}

__device__ __forceinline__ void attn_local_body(
    const ushort_t* __restrict__ QKV, ushort_t* __restrict__ O,
    int tile, int h, int b,
    ushort_t (*Ks)[72], ushort_t (*Vt)[72], ushort_t (*Ps)[72], float* lbuf)
{
    int tid = threadIdx.x;
    int lane = tid & 63;
    int wave = tid >> 6;
    int quad = lane >> 4, l15 = lane & 15;
    int wi = tile / 6, wj = tile % 6;

    bf16x8 aq[2];
    {
        int ql = wave * 16 + l15;
        int tok = (wi * 8 + (ql >> 3)) * 48 + wj * 8 + (ql & 7);
        const ushort_t* qbase = QKV + (size_t)(b * Lh + tok) * QS + 2304 + h * 64;
        #pragma unroll
        for (int step = 0; step < 2; ++step)
            aq[step] = *(const bf16x8*)(qbase + step * 32 + quad * 8);
    }

    float l_part = 0.f;
    f32x4 o_acc[4];
    #pragma unroll
    for (int t4 = 0; t4 < 4; ++t4) o_acc[t4] = (f32x4){0.f, 0.f, 0.f, 0.f};

    #pragma unroll
    for (int it = 0; it < 2; ++it) {
        int e = tid + it * 256;
        int row = e >> 3, g = e & 7;
        int tok = (wi * 8 + (row >> 3)) * 48 + wj * 8 + (row & 7);
        const ushort_t* base = QKV + (size_t)(b * Lh + tok) * QS + 2304 + h * 64 + g * 8;
        uint4 kvv = *(const uint4*)(base + 768);
        *(uint4*)&Ks[row][g * 8] = kvv;
        union { uint4 raw; ushort_t us[8]; } vv;
        vv.raw = *(const uint4*)(base + 1536);
        int col = row ^ (g << 3);
        #pragma unroll
        for (int j = 0; j < 8; ++j) Vt[g * 8 + j][col] = vv.us[j];
    }
    __syncthreads();

    f32x4 s4[4];
    #pragma unroll
    for (int j4 = 0; j4 < 4; ++j4) s4[j4] = (f32x4){0.f, 0.f, 0.f, 0.f};
    #pragma unroll
    for (int step = 0; step < 2; ++step) {
        bf16x8 bk[4];
        #pragma unroll
        for (int j4 = 0; j4 < 4; ++j4)
            bk[j4] = *(const bf16x8*)&Ks[j4 * 16 + l15][step * 32 + quad * 8];
        #pragma unroll
        for (int j4 = 0; j4 < 4; ++j4)
            s4[j4] = MFMA16(bk[j4], aq[step], s4[j4]);
    }
    int p0 = wave * 16;
    #pragma unroll
    for (int j4 = 0; j4 < 4; ++j4) {
        float e0 = __expf(s4[j4][0] * 0.125f);
        float e1 = __expf(s4[j4][1] * 0.125f);
        float e2 = __expf(s4[j4][2] * 0.125f);
        float e3 = __expf(s4[j4][3] * 0.125f);
        l_part += (e0 + e1) + (e2 + e3);
        uint_t a01 = __builtin_amdgcn_perm(__float_as_uint(e1), __float_as_uint(e0), 0x07060302u);
        uint_t a23 = __builtin_amdgcn_perm(__float_as_uint(e3), __float_as_uint(e2), 0x07060302u);
        *(uint2*)&Ps[p0 + l15][j4 * 16 + quad * 4] = make_uint2(a01, a23);
    }
    #pragma unroll
    for (int step = 0; step < 2; ++step) {
        bf16x8 bv[4];
        #pragma unroll
        for (int t4 = 0; t4 < 4; ++t4) {
            int dd = t4 * 16 + l15;
            int cb = ((step * 4 + quad) ^ ((dd >> 3) & 7)) * 8;
            bv[t4] = *(const bf16x8*)&Vt[dd][cb];
        }
        bf16x8 a = *(const bf16x8*)&Ps[p0 + l15][step * 32 + quad * 8];
        #pragma unroll
        for (int t4 = 0; t4 < 4; ++t4)
            o_acc[t4] = MFMA16(a, bv[t4], o_acc[t4]);
    }

    {
        float v = l_part;
        v += __shfl_xor(v, 16, 64);
        v += __shfl_xor(v, 32, 64);
        if (quad == 0) lbuf[wave * 16 + l15] = v;
    }
    #pragma unroll
    for (int r = 0; r < 4; ++r) {
        int ql = wave * 16 + quad * 4 + r;
        float inv = 1.0f / lbuf[ql];
        int tok = (wi * 8 + (ql >> 3)) * 48 + wj * 8 + (ql & 7);
        #pragma unroll
        for (int t4 = 0; t4 < 4; ++t4)
            O[(size_t)(b * Lh + tok) * Ch + h * 64 + t4 * 16 + l15] =
                f2bf(o_acc[t4][r] * inv);
    }
}

__global__ __launch_bounds__(256)
void attn_fused_kernel(const ushort_t* __restrict__ QKV, const float* __restrict__ fg,
                       ushort_t* __restrict__ ctxg, ushort_t* __restrict__ ctxl)
{
    __shared__ ushort_t Ks[64][72];
    __shared__ ushort_t Vt[64][72];
    __shared__ ushort_t Ps[128][72];
    __shared__ float fgs[64];
    __shared__ float lbuf[128];

    int gid = blockIdx.x;
    if (gid < 432) {
        int tile = gid % 18;
        int h = (gid / 18) % NHh;
        int b = gid / (18 * NHh);
        attn_global_body(QKV, fg, ctxg, tile, h, b, Ks, Vt, Ps, fgs, lbuf);
    } else {
        int rr = gid - 432;                     // 0..863
        int tile = rr % 36;
        int h = (rr / 36) % NHh;
        int b = rr / (36 * NHh);
        attn_local_body(QKV, ctxl, tile, h, b, Ks, Vt, Ps, lbuf);
    }
}

// ---------------------------------------------------------------- launch
extern "C" void kernel_launch(void* const* d_in, const int* in_sizes, int n_in,
                              void* d_out, int out_size, void* d_ws, size_t ws_size,
                              hipStream_t stream)
{
    const float* x       = (const float*)d_in[0];
    const float* mask    = (const float*)d_in[1];
    const float* w_qkv_g = (const float*)d_in[2];
    const float* b_qkv_g = (const float*)d_in[3];
    const float* w_o_g   = (const float*)d_in[4];
    const float* b_o_g   = (const float*)d_in[5];
    const float* w_qkv_l = (const float*)d_in[6];
    const float* b_qkv_l = (const float*)d_in[7];
    const float* w_o_l   = (const float*)d_in[8];
    const float* b_o_l   = (const float*)d_in[9];
    const float* ln1_w   = (const float*)d_in[10];
    const float* ln1_b   = (const float*)d_in[11];
    const float* ln2_w   = (const float*)d_in[12];
    const float* ln2_b   = (const float*)d_in[13];
    const float* w_fc1   = (const float*)d_in[14];
    const float* b_fc1   = (const float*)d_in[15];
    const float* w_fc2   = (const float*)d_in[16];
    const float* b_fc2   = (const float*)d_in[17];
    float* out = (float*)d_out;

    const size_t U = (size_t)Bh * Lh * Ch;           // 3,538,944
    char* p = (char*)d_ws;
    ushort_t* qkvb = (ushort_t*)p;        p += (size_t)4608 * 4608 * 2;  // [4608][4608] bf16
    ushort_t* midb = qkvb;                                               // [4608][3072] aliases
    ushort_t* ctxg = (ushort_t*)p;        p += U * 2;
    ushort_t* ctxl = (ushort_t*)p;        p += U * 2;
    ushort_t* xnb  = (ushort_t*)p;        p += U * 2;
    float*    x1   = (float*)p;           p += U * 4;
    ushort_t* wtq  = (ushort_t*)p;        p += (size_t)4608 * 768 * 2;   // qkv g|l concat
    ushort_t* wt_o_g = (ushort_t*)p;      p += (size_t)768 * 768 * 2;
    ushort_t* wt_o_l = (ushort_t*)p;      p += (size_t)768 * 768 * 2;
    ushort_t* wt_fc1 = (ushort_t*)p;      p += (size_t)3072 * 768 * 2;
    ushort_t* wt_fc2 = (ushort_t*)p;      p += (size_t)768 * 3072 * 2;
    float*    biasq  = (float*)p;         p += 4608 * 4;
    float*    fg     = (float*)p;         p += Bh * Lh * 4;
    float*    bgw    = (float*)p;

    const int Mrows = Bh * Lh;                   // 4608
    dim3 blk(256);

    // concat qkv biases (g then l)
    hipMemcpyAsync(biasq, b_qkv_g, 2304 * sizeof(float), hipMemcpyDeviceToDevice, stream);
    hipMemcpyAsync(biasq + 2304, b_qkv_l, 2304 * sizeof(float), hipMemcpyDeviceToDevice, stream);

    // all weight transposes in one dispatch
    transpose_all_kernel<<<2304, blk, 0, stream>>>(
        w_qkv_g, w_qkv_l, w_o_g, w_o_l, w_fc1, w_fc2,
        wtq, wt_o_g, wt_o_l, wt_fc1, wt_fc2);

    // LN1 -> bf16; fused masks
    layernorm_bf16_kernel<<<Mrows, blk, 0, stream>>>(x, ln1_w, ln1_b, xnb);
    mask_kernel<<<72, dim3(64), 0, stream>>>(mask, fg, bgw);

    // fused QKV GEMM for both branches (N=4608)
    gemm_bf16_t<128><<<dim3(4608 / 128, Mrows / 128), blk, 0, stream>>>(
        xnb, wtq, biasq, nullptr, qkvb, Mrows, 4608, Ch, 2, nullptr, nullptr);

    // fused attention: 432 global + 864 local blocks
    attn_fused_kernel<<<1296, blk, 0, stream>>>(qkvb, fg, ctxg, ctxl);

    // masked o-projections into x1
    gemm_bf16_t<64><<<dim3(Ch / 64, Mrows / 128), blk, 0, stream>>>(
        ctxg, wt_o_g, b_o_g, x, x1, Mrows, Ch, Ch, 4, fg, nullptr);
    gemm_bf16_t<64><<<dim3(Ch / 64, Mrows / 128), blk, 0, stream>>>(
        ctxl, wt_o_l, b_o_l, x1, x1, Mrows, Ch, Ch, 8, fg, bgw);

    // LN2 -> bf16
    layernorm_bf16_kernel<<<Mrows, blk, 0, stream>>>(x1, ln2_w, ln2_b, xnb);

    // MLP
    gemm_bf16_t<128><<<dim3(3072 / 128, Mrows / 128), blk, 0, stream>>>(
        xnb, wt_fc1, b_fc1, nullptr, midb, Mrows, 3072, Ch, 1 | 2, nullptr, nullptr);
    gemm_bf16_t<64><<<dim3(Ch / 64, Mrows / 128), blk, 0, stream>>>(
        midb, wt_fc2, b_fc2, x1, out, Mrows, Ch, 3072, 0, nullptr, nullptr);
}

// Round 10
// 421.545 us; speedup vs baseline: 1.2047x; 1.1705x over previous
//
#include <hip/hip_runtime.h>
#include <math.h>

#define Lh 2304
#define Ch 768
#define NHh 12
#define Bh 2
#define QS 4608   // row stride of fused qkv activation buffer (global q|k|v, local q|k|v)

typedef unsigned short ushort_t;
typedef unsigned int uint_t;
typedef __attribute__((ext_vector_type(8))) short bf16x8;
typedef __attribute__((ext_vector_type(4))) float f32x4;
#define MFMA16(a, b, c) __builtin_amdgcn_mfma_f32_16x16x32_bf16(a, b, c, 0, 0, 0)

__device__ __forceinline__ ushort_t f2bf(float f) {
    union { float f; uint_t u; } v; v.f = f;
    uint_t u = v.u + 0x7fffu + ((v.u >> 16) & 1u);   // RNE
    return (ushort_t)(u >> 16);
}

// async global->LDS, 16B/lane, dest = wave-uniform base + lane*16
__device__ __forceinline__ void llds16(ushort_t* dst, const ushort_t* src) {
    __builtin_amdgcn_global_load_lds(
        (__attribute__((address_space(1))) void*)(const_cast<ushort_t*>(src)),
        (__attribute__((address_space(3))) void*)dst, 16, 0, 0);
}

// ---------------------------------------------------------------- layernorm (fp32 in, bf16 out)
__global__ __launch_bounds__(256)
void layernorm_bf16_kernel(const float* __restrict__ x, const float* __restrict__ w,
                           const float* __restrict__ b, ushort_t* __restrict__ y)
{
    int row = blockIdx.x;
    int tid = threadIdx.x;
    const float* xr = x + (size_t)row * Ch;
    float v0 = xr[tid], v1 = xr[tid + 256], v2 = xr[tid + 512];
    __shared__ float red[256];
    red[tid] = v0 + v1 + v2;
    __syncthreads();
    for (int st = 128; st > 0; st >>= 1) {
        if (tid < st) red[tid] += red[tid + st];
        __syncthreads();
    }
    float mean = red[0] * (1.0f / 768.0f);
    __syncthreads();
    float d0 = v0 - mean, d1 = v1 - mean, d2 = v2 - mean;
    red[tid] = d0 * d0 + d1 * d1 + d2 * d2;
    __syncthreads();
    for (int st = 128; st > 0; st >>= 1) {
        if (tid < st) red[tid] += red[tid + st];
        __syncthreads();
    }
    float rstd = rsqrtf(red[0] * (1.0f / 768.0f) + 1e-6f);
    ushort_t* yr = y + (size_t)row * Ch;
    yr[tid]       = f2bf(d0 * rstd * w[tid]       + b[tid]);
    yr[tid + 256] = f2bf(d1 * rstd * w[tid + 256] + b[tid + 256]);
    yr[tid + 512] = f2bf(d2 * rstd * w[tid + 512] + b[tid + 512]);
}

// ---------------------------------------------------------------- fused mask kernel
__global__ __launch_bounds__(64)
void mask_kernel(const float* __restrict__ mask, float* __restrict__ fg,
                 float* __restrict__ bgw)
{
    int win = blockIdx.x;            // 0..71
    int b = win / 36, w = win % 36;
    int wi = w / 6, wj = w % 6;
    int lane = threadIdx.x;          // 64
    int i = wi * 8 + (lane >> 3), j = wj * 8 + (lane & 7);
    const float* mb = mask + (size_t)b * 192 * 192 + (size_t)(i * 4) * 192 + j * 4;
    float s = 0.0f;
    #pragma unroll
    for (int di = 0; di < 4; ++di) {
        float4 v = *(const float4*)(mb + (size_t)di * 192);
        s += v.x + v.y + v.z + v.w;
    }
    float f = (s * (1.0f / 16.0f) > 0.4f) ? 1.0f : 0.0f;
    fg[b * Lh + i * 48 + j] = f;
    unsigned long long bg = __ballot(f == 0.0f);
    if (lane == 0) bgw[win] = bg ? 1.0f : 0.0f;
}

// ---------------------------------------------------------------- batched weight cast+transpose
__global__ __launch_bounds__(256)
void transpose_all_kernel(const float* __restrict__ w_qkv_g, const float* __restrict__ w_qkv_l,
                          const float* __restrict__ w_o_g, const float* __restrict__ w_o_l,
                          const float* __restrict__ w_fc1, const float* __restrict__ w_fc2,
                          ushort_t* __restrict__ wtq, ushort_t* __restrict__ wt_o_g,
                          ushort_t* __restrict__ wt_o_l, ushort_t* __restrict__ wt_fc1,
                          ushort_t* __restrict__ wt_fc2)
{
    int blk = blockIdx.x;
    const float* W; ushort_t* D; int K, N, nx, bx;
    const size_t CC = (size_t)Ch * Ch;
    if (blk < 432)       { int t = blk / 144; bx = blk % 144;
                           W = w_qkv_g + t * CC; D = wtq + t * CC; K = 768; N = 768; nx = 12; }
    else if (blk < 864)  { int r = blk - 432; int t = r / 144; bx = r % 144;
                           W = w_qkv_l + t * CC; D = wtq + (size_t)2304 * 768 + t * CC;
                           K = 768; N = 768; nx = 12; }
    else if (blk < 1008) { bx = blk - 864;  W = w_o_g; D = wt_o_g; K = 768; N = 768; nx = 12; }
    else if (blk < 1152) { bx = blk - 1008; W = w_o_l; D = wt_o_l; K = 768; N = 768; nx = 12; }
    else if (blk < 1728) { bx = blk - 1152; W = w_fc1; D = wt_fc1; K = 768; N = 3072; nx = 48; }
    else                 { bx = blk - 1728; W = w_fc2; D = wt_fc2; K = 3072; N = 768; nx = 12; }
    int n0 = (bx % nx) * 64;
    int k0 = (bx / nx) * 64;
    int tid = threadIdx.x;
    __shared__ float T[64][65];
    #pragma unroll
    for (int i = 0; i < 16; ++i) {
        int lin = i * 256 + tid;
        int r = lin >> 6, c = lin & 63;
        T[r][c] = W[(size_t)(k0 + r) * N + n0 + c];
    }
    __syncthreads();
    #pragma unroll
    for (int i = 0; i < 16; ++i) {
        int lin = i * 256 + tid;
        int r = lin >> 6, c = lin & 63;
        D[(size_t)(n0 + r) * K + k0 + c] = f2bf(T[c][r]);
    }
}

// ---------------------------------------------------------------- bf16 MFMA GEMM (BM=128, BN template)
// Double-buffered LDS: one barrier/iter, async global_load_lds staging of tile k+1
// overlaps compute of tile k. XOR chunk swizzle via source addr (R7, proven).
// flags: 1=gelu, 2=bf16 out
template<int BNt>
__global__ __launch_bounds__(256)
void gemm_bf16_t(const ushort_t* __restrict__ A, const ushort_t* __restrict__ Bt,
                 const float* __restrict__ bias, const float* __restrict__ residual,
                 void* __restrict__ C, int M, int N, int K, int flags)
{
    __shared__ ushort_t AsL[2][128 * 32];
    __shared__ ushort_t BsL[2][BNt * 32];
    int bm = blockIdx.y * 128;
    int bn = blockIdx.x * BNt;
    int tid = threadIdx.x;
    int lane = tid & 63;
    int wave = tid >> 6;
    int wm = wave >> 1, wn = wave & 1;
    int quad = lane >> 4, l15 = lane & 15;
    constexpr int NJ = BNt / 32;

    int srow = lane >> 2;
    int sg8 = ((lane & 3) ^ ((lane >> 3) & 3)) * 8;
    int fsw = (l15 >> 1) & 3;

    f32x4 acc[4][NJ];
    #pragma unroll
    for (int i = 0; i < 4; ++i)
        #pragma unroll
        for (int j = 0; j < NJ; ++j)
            acc[i][j] = (f32x4){0.f, 0.f, 0.f, 0.f};

    int iters = K / 32;
    // stage buffer 0
    llds16(&AsL[0][wave * 512], A + (size_t)(bm + wave * 16 + srow) * K + sg8);
    llds16(&AsL[0][(wave + 4) * 512], A + (size_t)(bm + (wave + 4) * 16 + srow) * K + sg8);
    llds16(&BsL[0][wave * 512], Bt + (size_t)(bn + wave * 16 + srow) * K + sg8);
    if (BNt == 128)
        llds16(&BsL[0][(wave + 4) * 512], Bt + (size_t)(bn + (wave + 4) * 16 + srow) * K + sg8);

    for (int kt = 0; kt < iters; ++kt) {
        int cur = kt & 1;
        __syncthreads();   // drains vmcnt -> buf[cur] ready; all waves done with buf[1-cur]

        bf16x8 af[4], bfr[NJ];
        #pragma unroll
        for (int i = 0; i < 4; ++i)
            af[i] = *(const bf16x8*)&AsL[cur][(wm * 64 + i * 16 + l15) * 32 + ((quad ^ fsw) * 8)];
        #pragma unroll
        for (int j = 0; j < NJ; ++j)
            bfr[j] = *(const bf16x8*)&BsL[cur][(wn * (BNt / 2) + j * 16 + l15) * 32 + ((quad ^ fsw) * 8)];

        if (kt + 1 < iters) {
            int k0 = (kt + 1) * 32;
            int nxt = 1 - cur;
            llds16(&AsL[nxt][wave * 512], A + (size_t)(bm + wave * 16 + srow) * K + k0 + sg8);
            llds16(&AsL[nxt][(wave + 4) * 512], A + (size_t)(bm + (wave + 4) * 16 + srow) * K + k0 + sg8);
            llds16(&BsL[nxt][wave * 512], Bt + (size_t)(bn + wave * 16 + srow) * K + k0 + sg8);
            if (BNt == 128)
                llds16(&BsL[nxt][(wave + 4) * 512], Bt + (size_t)(bn + (wave + 4) * 16 + srow) * K + k0 + sg8);
        }

        #pragma unroll
        for (int i = 0; i < 4; ++i)
            #pragma unroll
            for (int j = 0; j < NJ; ++j)
                acc[i][j] = MFMA16(af[i], bfr[j], acc[i][j]);
    }

    float bia[NJ];
    #pragma unroll
    for (int j = 0; j < NJ; ++j) bia[j] = bias[bn + wn * (BNt / 2) + j * 16 + l15];

    #pragma unroll
    for (int i = 0; i < 4; ++i) {
        #pragma unroll
        for (int r = 0; r < 4; ++r) {
            int row = bm + wm * 64 + i * 16 + quad * 4 + r;
            #pragma unroll
            for (int j = 0; j < NJ; ++j) {
                int col = bn + wn * (BNt / 2) + j * 16 + l15;
                float v = acc[i][j][r] + bia[j];
                if (flags & 1) v = v * 0.5f * (1.0f + erff(v * 0.70710678f));
                float o = residual ? residual[(size_t)row * N + col] + v : v;
                if (flags & 2) ((ushort_t*)C)[(size_t)row * N + col] = f2bf(o);
                else           ((float*)C)[(size_t)row * N + col] = o;
            }
        }
    }
}

// ---------------------------------------------------------------- dual o-projection
// One dispatch: vg = ctxg@Wg^T+bg, vl = ctxl@Wl^T+bl (two sequential dbuf K-loops),
// epilogue x1 = x + (fg ? vg : (bgwin ? vl : 0)). BM=128, BN=64, K=768.
__global__ __launch_bounds__(256)
void oproj_dual_kernel(const ushort_t* __restrict__ ctxg, const ushort_t* __restrict__ ctxl,
                       const ushort_t* __restrict__ Wg, const ushort_t* __restrict__ Wl,
                       const float* __restrict__ biasg, const float* __restrict__ biasl,
                       const float* __restrict__ x, float* __restrict__ x1,
                       const float* __restrict__ fg, const float* __restrict__ bgw)
{
    __shared__ ushort_t AsL[2][128 * 32];
    __shared__ ushort_t BsL[2][64 * 32];
    int bm = blockIdx.y * 128;
    int bn = blockIdx.x * 64;
    int tid = threadIdx.x;
    int lane = tid & 63;
    int wave = tid >> 6;
    int wm = wave >> 1, wn = wave & 1;
    int quad = lane >> 4, l15 = lane & 15;

    int srow = lane >> 2;
    int sg8 = ((lane & 3) ^ ((lane >> 3) & 3)) * 8;
    int fsw = (l15 >> 1) & 3;
    const int K = Ch, N = Ch, iters = Ch / 32;

    f32x4 accg[4][2], accl[4][2];
    #pragma unroll
    for (int i = 0; i < 4; ++i)
        #pragma unroll
        for (int j = 0; j < 2; ++j) {
            accg[i][j] = (f32x4){0.f, 0.f, 0.f, 0.f};
            accl[i][j] = (f32x4){0.f, 0.f, 0.f, 0.f};
        }

    #pragma unroll
    for (int pass = 0; pass < 2; ++pass) {
        const ushort_t* A = pass ? ctxl : ctxg;
        const ushort_t* Bt = pass ? Wl : Wg;
        if (pass) __syncthreads();   // all waves done reading pass-0's last buffer
        llds16(&AsL[0][wave * 512], A + (size_t)(bm + wave * 16 + srow) * K + sg8);
        llds16(&AsL[0][(wave + 4) * 512], A + (size_t)(bm + (wave + 4) * 16 + srow) * K + sg8);
        llds16(&BsL[0][wave * 512], Bt + (size_t)(bn + wave * 16 + srow) * K + sg8);

        for (int kt = 0; kt < iters; ++kt) {
            int cur = kt & 1;
            __syncthreads();
            bf16x8 af[4], bfr[2];
            #pragma unroll
            for (int i = 0; i < 4; ++i)
                af[i] = *(const bf16x8*)&AsL[cur][(wm * 64 + i * 16 + l15) * 32 + ((quad ^ fsw) * 8)];
            #pragma unroll
            for (int j = 0; j < 2; ++j)
                bfr[j] = *(const bf16x8*)&BsL[cur][(wn * 32 + j * 16 + l15) * 32 + ((quad ^ fsw) * 8)];
            if (kt + 1 < iters) {
                int k0 = (kt + 1) * 32;
                int nxt = 1 - cur;
                llds16(&AsL[nxt][wave * 512], A + (size_t)(bm + wave * 16 + srow) * K + k0 + sg8);
                llds16(&AsL[nxt][(wave + 4) * 512], A + (size_t)(bm + (wave + 4) * 16 + srow) * K + k0 + sg8);
                llds16(&BsL[nxt][wave * 512], Bt + (size_t)(bn + wave * 16 + srow) * K + k0 + sg8);
            }
            if (pass == 0) {
                #pragma unroll
                for (int i = 0; i < 4; ++i)
                    #pragma unroll
                    for (int j = 0; j < 2; ++j)
                        accg[i][j] = MFMA16(af[i], bfr[j], accg[i][j]);
            } else {
                #pragma unroll
                for (int i = 0; i < 4; ++i)
                    #pragma unroll
                    for (int j = 0; j < 2; ++j)
                        accl[i][j] = MFMA16(af[i], bfr[j], accl[i][j]);
            }
        }
    }

    float bg_[2], bl_[2];
    #pragma unroll
    for (int j = 0; j < 2; ++j) {
        bg_[j] = biasg[bn + wn * 32 + j * 16 + l15];
        bl_[j] = biasl[bn + wn * 32 + j * 16 + l15];
    }

    #pragma unroll
    for (int i = 0; i < 4; ++i) {
        #pragma unroll
        for (int r = 0; r < 4; ++r) {
            int row = bm + wm * 64 + i * 16 + quad * 4 + r;
            int bb = (row >= Lh) ? 1 : 0;
            int n = row - bb * Lh;
            int ii = n / 48, jj = n % 48;
            float keepg = (fg[row] != 0.0f) ? 1.0f : 0.0f;
            float keepl = (keepg == 0.0f &&
                           bgw[bb * 36 + (ii >> 3) * 6 + (jj >> 3)] != 0.0f) ? 1.0f : 0.0f;
            #pragma unroll
            for (int j = 0; j < 2; ++j) {
                int col = bn + wn * 32 + j * 16 + l15;
                float vg = accg[i][j][r] + bg_[j];
                float vl = accl[i][j][r] + bl_[j];
                x1[(size_t)row * N + col] =
                    x[(size_t)row * N + col] + keepg * vg + keepl * vl;
            }
        }
    }
}

// ---------------------------------------------------------------- fused attention (global + local)  [unchanged R9]
__device__ __forceinline__ void attn_global_body(
    const ushort_t* __restrict__ QKV, const float* __restrict__ fg,
    ushort_t* __restrict__ O, int tile, int h, int b,
    ushort_t (*Ks)[72], ushort_t (*Vt)[72], ushort_t (*Ps)[72],
    float* fgs, float* lbuf)
{
    int tid = threadIdx.x;
    int lane = tid & 63;
    int wave = tid >> 6;
    int quad = lane >> 4, l15 = lane & 15;

    bf16x8 aq[2][2];
    #pragma unroll
    for (int s = 0; s < 2; ++s) {
        int ql = wave * 32 + s * 16 + l15;
        int tok = tile * 128 + ql;
        const ushort_t* qbase = QKV + (size_t)(b * Lh + tok) * QS + h * 64;
        #pragma unroll
        for (int step = 0; step < 2; ++step)
            aq[s][step] = *(const bf16x8*)(qbase + step * 32 + quad * 8);
    }

    float l_part[2] = {0.f, 0.f};
    f32x4 o_acc[2][4];
    #pragma unroll
    for (int s = 0; s < 2; ++s)
        #pragma unroll
        for (int t4 = 0; t4 < 4; ++t4) o_acc[s][t4] = (f32x4){0.f, 0.f, 0.f, 0.f};

    uint4 kx[2], vx[2];
    #pragma unroll
    for (int it = 0; it < 2; ++it) {
        int e = tid + it * 256;
        int row = e >> 3, g = e & 7;
        const ushort_t* base = QKV + (size_t)(b * Lh + row) * QS + h * 64 + g * 8;
        kx[it] = *(const uint4*)(base + 768);
        vx[it] = *(const uint4*)(base + 1536);
    }
    float fgn = 0.f;
    if (tid < 64) fgn = fg[b * Lh + tid];

    for (int kt = 0; kt < 36; ++kt) {
        __syncthreads();
        #pragma unroll
        for (int it = 0; it < 2; ++it) {
            int e = tid + it * 256;
            int row = e >> 3, g = e & 7;
            *(uint4*)&Ks[row][g * 8] = kx[it];
            union { uint4 raw; ushort_t us[8]; } vv;
            vv.raw = vx[it];
            int col = row ^ (g << 3);
            #pragma unroll
            for (int j = 0; j < 8; ++j) Vt[g * 8 + j][col] = vv.us[j];
        }
        if (tid < 64) fgs[tid] = (fgn - 1.0f) * 1e9f;
        __syncthreads();

        if (kt + 1 < 36) {
            #pragma unroll
            for (int it = 0; it < 2; ++it) {
                int e = tid + it * 256;
                int row = e >> 3, g = e & 7;
                int tok = (kt + 1) * 64 + row;
                const ushort_t* base = QKV + (size_t)(b * Lh + tok) * QS + h * 64 + g * 8;
                kx[it] = *(const uint4*)(base + 768);
                vx[it] = *(const uint4*)(base + 1536);
            }
            if (tid < 64) fgn = fg[b * Lh + (kt + 1) * 64 + tid];
        }

        f32x4 s4[2][4];
        #pragma unroll
        for (int s = 0; s < 2; ++s)
            #pragma unroll
            for (int j4 = 0; j4 < 4; ++j4) s4[s][j4] = (f32x4){0.f, 0.f, 0.f, 0.f};
        #pragma unroll
        for (int step = 0; step < 2; ++step) {
            bf16x8 bk[4];
            #pragma unroll
            for (int j4 = 0; j4 < 4; ++j4)
                bk[j4] = *(const bf16x8*)&Ks[j4 * 16 + l15][step * 32 + quad * 8];
            #pragma unroll
            for (int s = 0; s < 2; ++s)
                #pragma unroll
                for (int j4 = 0; j4 < 4; ++j4)
                    s4[s][j4] = MFMA16(bk[j4], aq[s][step], s4[s][j4]);
        }
        #pragma unroll
        for (int s = 0; s < 2; ++s) {
            int p0 = wave * 32 + s * 16;
            #pragma unroll
            for (int j4 = 0; j4 < 4; ++j4) {
                float4 mb4 = *(const float4*)&fgs[j4 * 16 + quad * 4];
                float e0 = __expf(s4[s][j4][0] * 0.125f + mb4.x);
                float e1 = __expf(s4[s][j4][1] * 0.125f + mb4.y);
                float e2 = __expf(s4[s][j4][2] * 0.125f + mb4.z);
                float e3 = __expf(s4[s][j4][3] * 0.125f + mb4.w);
                l_part[s] += (e0 + e1) + (e2 + e3);
                uint_t a01 = __builtin_amdgcn_perm(__float_as_uint(e1), __float_as_uint(e0), 0x07060302u);
                uint_t a23 = __builtin_amdgcn_perm(__float_as_uint(e3), __float_as_uint(e2), 0x07060302u);
                *(uint2*)&Ps[p0 + l15][j4 * 16 + quad * 4] = make_uint2(a01, a23);
            }
        }
        #pragma unroll
        for (int step = 0; step < 2; ++step) {
            bf16x8 bv[4];
            #pragma unroll
            for (int t4 = 0; t4 < 4; ++t4) {
                int dd = t4 * 16 + l15;
                int cb = ((step * 4 + quad) ^ ((dd >> 3) & 7)) * 8;
                bv[t4] = *(const bf16x8*)&Vt[dd][cb];
            }
            #pragma unroll
            for (int s = 0; s < 2; ++s) {
                int p0 = wave * 32 + s * 16;
                bf16x8 a = *(const bf16x8*)&Ps[p0 + l15][step * 32 + quad * 8];
                #pragma unroll
                for (int t4 = 0; t4 < 4; ++t4)
                    o_acc[s][t4] = MFMA16(a, bv[t4], o_acc[s][t4]);
            }
        }
    }

    #pragma unroll
    for (int s = 0; s < 2; ++s) {
        float v = l_part[s];
        v += __shfl_xor(v, 16, 64);
        v += __shfl_xor(v, 32, 64);
        if (quad == 0) lbuf[wave * 32 + s * 16 + l15] = v;
    }
    #pragma unroll
    for (int s = 0; s < 2; ++s) {
        #pragma unroll
        for (int r = 0; r < 4; ++r) {
            int ql = wave * 32 + s * 16 + quad * 4 + r;
            float inv = 1.0f / lbuf[ql];
            int tok = tile * 128 + ql;
            #pragma unroll
            for (int t4 = 0; t4 < 4; ++t4)
                O[(size_t)(b * Lh + tok) * Ch + h * 64 + t4 * 16 + l15] =
                    f2bf(o_acc[s][t4][r] * inv);
        }
    }
}

__device__ __forceinline__ void attn_local_body(
    const ushort_t* __restrict__ QKV, ushort_t* __restrict__ O,
    int tile, int h, int b,
    ushort_t (*Ks)[72], ushort_t (*Vt)[72], ushort_t (*Ps)[72], float* lbuf)
{
    int tid = threadIdx.x;
    int lane = tid & 63;
    int wave = tid >> 6;
    int quad = lane >> 4, l15 = lane & 15;
    int wi = tile / 6, wj = tile % 6;

    bf16x8 aq[2];
    {
        int ql = wave * 16 + l15;
        int tok = (wi * 8 + (ql >> 3)) * 48 + wj * 8 + (ql & 7);
        const ushort_t* qbase = QKV + (size_t)(b * Lh + tok) * QS + 2304 + h * 64;
        #pragma unroll
        for (int step = 0; step < 2; ++step)
            aq[step] = *(const bf16x8*)(qbase + step * 32 + quad * 8);
    }

    float l_part = 0.f;
    f32x4 o_acc[4];
    #pragma unroll
    for (int t4 = 0; t4 < 4; ++t4) o_acc[t4] = (f32x4){0.f, 0.f, 0.f, 0.f};

    #pragma unroll
    for (int it = 0; it < 2; ++it) {
        int e = tid + it * 256;
        int row = e >> 3, g = e & 7;
        int tok = (wi * 8 + (row >> 3)) * 48 + wj * 8 + (row & 7);
        const ushort_t* base = QKV + (size_t)(b * Lh + tok) * QS + 2304 + h * 64 + g * 8;
        uint4 kvv = *(const uint4*)(base + 768);
        *(uint4*)&Ks[row][g * 8] = kvv;
        union { uint4 raw; ushort_t us[8]; } vv;
        vv.raw = *(const uint4*)(base + 1536);
        int col = row ^ (g << 3);
        #pragma unroll
        for (int j = 0; j < 8; ++j) Vt[g * 8 + j][col] = vv.us[j];
    }
    __syncthreads();

    f32x4 s4[4];
    #pragma unroll
    for (int j4 = 0; j4 < 4; ++j4) s4[j4] = (f32x4){0.f, 0.f, 0.f, 0.f};
    #pragma unroll
    for (int step = 0; step < 2; ++step) {
        bf16x8 bk[4];
        #pragma unroll
        for (int j4 = 0; j4 < 4; ++j4)
            bk[j4] = *(const bf16x8*)&Ks[j4 * 16 + l15][step * 32 + quad * 8];
        #pragma unroll
        for (int j4 = 0; j4 < 4; ++j4)
            s4[j4] = MFMA16(bk[j4], aq[step], s4[j4]);
    }
    int p0 = wave * 16;
    #pragma unroll
    for (int j4 = 0; j4 < 4; ++j4) {
        float e0 = __expf(s4[j4][0] * 0.125f);
        float e1 = __expf(s4[j4][1] * 0.125f);
        float e2 = __expf(s4[j4][2] * 0.125f);
        float e3 = __expf(s4[j4][3] * 0.125f);
        l_part += (e0 + e1) + (e2 + e3);
        uint_t a01 = __builtin_amdgcn_perm(__float_as_uint(e1), __float_as_uint(e0), 0x07060302u);
        uint_t a23 = __builtin_amdgcn_perm(__float_as_uint(e3), __float_as_uint(e2), 0x07060302u);
        *(uint2*)&Ps[p0 + l15][j4 * 16 + quad * 4] = make_uint2(a01, a23);
    }
    #pragma unroll
    for (int step = 0; step < 2; ++step) {
        bf16x8 bv[4];
        #pragma unroll
        for (int t4 = 0; t4 < 4; ++t4) {
            int dd = t4 * 16 + l15;
            int cb = ((step * 4 + quad) ^ ((dd >> 3) & 7)) * 8;
            bv[t4] = *(const bf16x8*)&Vt[dd][cb];
        }
        bf16x8 a = *(const bf16x8*)&Ps[p0 + l15][step * 32 + quad * 8];
        #pragma unroll
        for (int t4 = 0; t4 < 4; ++t4)
            o_acc[t4] = MFMA16(a, bv[t4], o_acc[t4]);
    }

    {
        float v = l_part;
        v += __shfl_xor(v, 16, 64);
        v += __shfl_xor(v, 32, 64);
        if (quad == 0) lbuf[wave * 16 + l15] = v;
    }
    #pragma unroll
    for (int r = 0; r < 4; ++r) {
        int ql = wave * 16 + quad * 4 + r;
        float inv = 1.0f / lbuf[ql];
        int tok = (wi * 8 + (ql >> 3)) * 48 + wj * 8 + (ql & 7);
        #pragma unroll
        for (int t4 = 0; t4 < 4; ++t4)
            O[(size_t)(b * Lh + tok) * Ch + h * 64 + t4 * 16 + l15] =
                f2bf(o_acc[t4][r] * inv);
    }
}

__global__ __launch_bounds__(256)
void attn_fused_kernel(const ushort_t* __restrict__ QKV, const float* __restrict__ fg,
                       ushort_t* __restrict__ ctxg, ushort_t* __restrict__ ctxl)
{
    __shared__ ushort_t Ks[64][72];
    __shared__ ushort_t Vt[64][72];
    __shared__ ushort_t Ps[128][72];
    __shared__ float fgs[64];
    __shared__ float lbuf[128];

    int gid = blockIdx.x;
    if (gid < 432) {
        int tile = gid % 18;
        int h = (gid / 18) % NHh;
        int b = gid / (18 * NHh);
        attn_global_body(QKV, fg, ctxg, tile, h, b, Ks, Vt, Ps, fgs, lbuf);
    } else {
        int rr = gid - 432;
        int tile = rr % 36;
        int h = (rr / 36) % NHh;
        int b = rr / (36 * NHh);
        attn_local_body(QKV, ctxl, tile, h, b, Ks, Vt, Ps, lbuf);
    }
}

// ---------------------------------------------------------------- launch
extern "C" void kernel_launch(void* const* d_in, const int* in_sizes, int n_in,
                              void* d_out, int out_size, void* d_ws, size_t ws_size,
                              hipStream_t stream)
{
    const float* x       = (const float*)d_in[0];
    const float* mask    = (const float*)d_in[1];
    const float* w_qkv_g = (const float*)d_in[2];
    const float* b_qkv_g = (const float*)d_in[3];
    const float* w_o_g   = (const float*)d_in[4];
    const float* b_o_g   = (const float*)d_in[5];
    const float* w_qkv_l = (const float*)d_in[6];
    const float* b_qkv_l = (const float*)d_in[7];
    const float* w_o_l   = (const float*)d_in[8];
    const float* b_o_l   = (const float*)d_in[9];
    const float* ln1_w   = (const float*)d_in[10];
    const float* ln1_b   = (const float*)d_in[11];
    const float* ln2_w   = (const float*)d_in[12];
    const float* ln2_b   = (const float*)d_in[13];
    const float* w_fc1   = (const float*)d_in[14];
    const float* b_fc1   = (const float*)d_in[15];
    const float* w_fc2   = (const float*)d_in[16];
    const float* b_fc2   = (const float*)d_in[17];
    float* out = (float*)d_out;

    const size_t U = (size_t)Bh * Lh * Ch;           // 3,538,944
    char* p = (char*)d_ws;
    ushort_t* qkvb = (ushort_t*)p;        p += (size_t)4608 * 4608 * 2;  // [4608][4608] bf16
    ushort_t* midb = qkvb;                                               // [4608][3072] aliases
    ushort_t* ctxg = (ushort_t*)p;        p += U * 2;
    ushort_t* ctxl = (ushort_t*)p;        p += U * 2;
    ushort_t* xnb  = (ushort_t*)p;        p += U * 2;
    float*    x1   = (float*)p;           p += U * 4;
    ushort_t* wtq  = (ushort_t*)p;        p += (size_t)4608 * 768 * 2;   // qkv g|l concat
    ushort_t* wt_o_g = (ushort_t*)p;      p += (size_t)768 * 768 * 2;
    ushort_t* wt_o_l = (ushort_t*)p;      p += (size_t)768 * 768 * 2;
    ushort_t* wt_fc1 = (ushort_t*)p;      p += (size_t)3072 * 768 * 2;
    ushort_t* wt_fc2 = (ushort_t*)p;      p += (size_t)768 * 3072 * 2;
    float*    biasq  = (float*)p;         p += 4608 * 4;
    float*    fg     = (float*)p;         p += Bh * Lh * 4;
    float*    bgw    = (float*)p;

    const int Mrows = Bh * Lh;                   // 4608
    dim3 blk(256);

    hipMemcpyAsync(biasq, b_qkv_g, 2304 * sizeof(float), hipMemcpyDeviceToDevice, stream);
    hipMemcpyAsync(biasq + 2304, b_qkv_l, 2304 * sizeof(float), hipMemcpyDeviceToDevice, stream);

    transpose_all_kernel<<<2304, blk, 0, stream>>>(
        w_qkv_g, w_qkv_l, w_o_g, w_o_l, w_fc1, w_fc2,
        wtq, wt_o_g, wt_o_l, wt_fc1, wt_fc2);

    layernorm_bf16_kernel<<<Mrows, blk, 0, stream>>>(x, ln1_w, ln1_b, xnb);
    mask_kernel<<<72, dim3(64), 0, stream>>>(mask, fg, bgw);

    // fused QKV GEMM for both branches (N=4608)
    gemm_bf16_t<128><<<dim3(4608 / 128, Mrows / 128), blk, 0, stream>>>(
        xnb, wtq, biasq, nullptr, qkvb, Mrows, 4608, Ch, 2);

    // fused attention: 432 global + 864 local blocks
    attn_fused_kernel<<<1296, blk, 0, stream>>>(qkvb, fg, ctxg, ctxl);

    // dual masked o-projection -> x1 (one dispatch)
    oproj_dual_kernel<<<dim3(Ch / 64, Mrows / 128), blk, 0, stream>>>(
        ctxg, ctxl, wt_o_g, wt_o_l, b_o_g, b_o_l, x, x1, fg, bgw);

    layernorm_bf16_kernel<<<Mrows, blk, 0, stream>>>(x1, ln2_w, ln2_b, xnb);

    // MLP
    gemm_bf16_t<128><<<dim3(3072 / 128, Mrows / 128), blk, 0, stream>>>(
        xnb, wt_fc1, b_fc1, nullptr, midb, Mrows, 3072, Ch, 1 | 2);
    gemm_bf16_t<64><<<dim3(Ch / 64, Mrows / 128), blk, 0, stream>>>(
        midb, wt_fc2, b_fc2, x1, out, Mrows, Ch, 3072, 0);
}

// Round 11
// 410.956 us; speedup vs baseline: 1.2357x; 1.0258x over previous
//
#include <hip/hip_runtime.h>
#include <math.h>

#define Lh 2304
#define Ch 768
#define NHh 12
#define Bh 2
#define QS 4608   // row stride of fused qkv activation buffer (global q|k|v, local q|k|v)

typedef unsigned short ushort_t;
typedef unsigned int uint_t;
typedef __attribute__((ext_vector_type(8))) short bf16x8;
typedef __attribute__((ext_vector_type(4))) float f32x4;
#define MFMA16(a, b, c) __builtin_amdgcn_mfma_f32_16x16x32_bf16(a, b, c, 0, 0, 0)

__device__ __forceinline__ ushort_t f2bf(float f) {
    union { float f; uint_t u; } v; v.f = f;
    uint_t u = v.u + 0x7fffu + ((v.u >> 16) & 1u);   // RNE
    return (ushort_t)(u >> 16);
}
// pack 2 fp32 -> 2 bf16 (RNE) into one u32
__device__ __forceinline__ uint_t pack2bf(float a, float b) {
    return (uint_t)f2bf(a) | ((uint_t)f2bf(b) << 16);
}

// async global->LDS, 16B/lane, dest = wave-uniform base + lane*16
__device__ __forceinline__ void llds16(ushort_t* dst, const ushort_t* src) {
    __builtin_amdgcn_global_load_lds(
        (__attribute__((address_space(1))) void*)(const_cast<ushort_t*>(src)),
        (__attribute__((address_space(3))) void*)dst, 16, 0, 0);
}

// ---------------------------------------------------------------- layernorm (fp32 in, bf16 out)
__global__ __launch_bounds__(256)
void layernorm_bf16_kernel(const float* __restrict__ x, const float* __restrict__ w,
                           const float* __restrict__ b, ushort_t* __restrict__ y)
{
    int row = blockIdx.x;
    int tid = threadIdx.x;
    const float* xr = x + (size_t)row * Ch;
    float v0 = xr[tid], v1 = xr[tid + 256], v2 = xr[tid + 512];
    __shared__ float red[256];
    red[tid] = v0 + v1 + v2;
    __syncthreads();
    for (int st = 128; st > 0; st >>= 1) {
        if (tid < st) red[tid] += red[tid + st];
        __syncthreads();
    }
    float mean = red[0] * (1.0f / 768.0f);
    __syncthreads();
    float d0 = v0 - mean, d1 = v1 - mean, d2 = v2 - mean;
    red[tid] = d0 * d0 + d1 * d1 + d2 * d2;
    __syncthreads();
    for (int st = 128; st > 0; st >>= 1) {
        if (tid < st) red[tid] += red[tid + st];
        __syncthreads();
    }
    float rstd = rsqrtf(red[0] * (1.0f / 768.0f) + 1e-6f);
    ushort_t* yr = y + (size_t)row * Ch;
    yr[tid]       = f2bf(d0 * rstd * w[tid]       + b[tid]);
    yr[tid + 256] = f2bf(d1 * rstd * w[tid + 256] + b[tid + 256]);
    yr[tid + 512] = f2bf(d2 * rstd * w[tid + 512] + b[tid + 512]);
}

// ---------------------------------------------------------------- fused mask kernel
__global__ __launch_bounds__(64)
void mask_kernel(const float* __restrict__ mask, float* __restrict__ fg,
                 float* __restrict__ bgw)
{
    int win = blockIdx.x;            // 0..71
    int b = win / 36, w = win % 36;
    int wi = w / 6, wj = w % 6;
    int lane = threadIdx.x;          // 64
    int i = wi * 8 + (lane >> 3), j = wj * 8 + (lane & 7);
    const float* mb = mask + (size_t)b * 192 * 192 + (size_t)(i * 4) * 192 + j * 4;
    float s = 0.0f;
    #pragma unroll
    for (int di = 0; di < 4; ++di) {
        float4 v = *(const float4*)(mb + (size_t)di * 192);
        s += v.x + v.y + v.z + v.w;
    }
    float f = (s * (1.0f / 16.0f) > 0.4f) ? 1.0f : 0.0f;
    fg[b * Lh + i * 48 + j] = f;
    unsigned long long bg = __ballot(f == 0.0f);
    if (lane == 0) bgw[win] = bg ? 1.0f : 0.0f;
}

// ---------------------------------------------------------------- batched weight cast+transpose
__global__ __launch_bounds__(256)
void transpose_all_kernel(const float* __restrict__ w_qkv_g, const float* __restrict__ w_qkv_l,
                          const float* __restrict__ w_o_g, const float* __restrict__ w_o_l,
                          const float* __restrict__ w_fc1, const float* __restrict__ w_fc2,
                          ushort_t* __restrict__ wtq, ushort_t* __restrict__ wt_o_g,
                          ushort_t* __restrict__ wt_o_l, ushort_t* __restrict__ wt_fc1,
                          ushort_t* __restrict__ wt_fc2)
{
    int blk = blockIdx.x;
    const float* W; ushort_t* D; int K, N, nx, bx;
    const size_t CC = (size_t)Ch * Ch;
    if (blk < 432)       { int t = blk / 144; bx = blk % 144;
                           W = w_qkv_g + t * CC; D = wtq + t * CC; K = 768; N = 768; nx = 12; }
    else if (blk < 864)  { int r = blk - 432; int t = r / 144; bx = r % 144;
                           W = w_qkv_l + t * CC; D = wtq + (size_t)2304 * 768 + t * CC;
                           K = 768; N = 768; nx = 12; }
    else if (blk < 1008) { bx = blk - 864;  W = w_o_g; D = wt_o_g; K = 768; N = 768; nx = 12; }
    else if (blk < 1152) { bx = blk - 1008; W = w_o_l; D = wt_o_l; K = 768; N = 768; nx = 12; }
    else if (blk < 1728) { bx = blk - 1152; W = w_fc1; D = wt_fc1; K = 768; N = 3072; nx = 48; }
    else                 { bx = blk - 1728; W = w_fc2; D = wt_fc2; K = 3072; N = 768; nx = 12; }
    int n0 = (bx % nx) * 64;
    int k0 = (bx / nx) * 64;
    int tid = threadIdx.x;
    __shared__ float T[64][65];
    #pragma unroll
    for (int i = 0; i < 16; ++i) {
        int lin = i * 256 + tid;
        int r = lin >> 6, c = lin & 63;
        T[r][c] = W[(size_t)(k0 + r) * N + n0 + c];
    }
    __syncthreads();
    // vectorized: each unit = (n-row r, 4 consecutive k) -> one b64 store
    #pragma unroll
    for (int i = 0; i < 4; ++i) {
        int lin = i * 256 + tid;          // 0..1023
        int r = lin >> 4, c0 = (lin & 15) * 4;
        uint_t lo = pack2bf(T[c0][r], T[c0 + 1][r]);
        uint_t hi = pack2bf(T[c0 + 2][r], T[c0 + 3][r]);
        *(uint2*)&D[(size_t)(n0 + r) * K + k0 + c0] = make_uint2(lo, hi);
    }
}

// ---------------------------------------------------------------- bf16 MFMA GEMM (BM=128, BN template)
// Double-buffered LDS (R10). MFMA operands SWAPPED -> transposed C-layout:
// lane l15 = output row, quad*4+r = 4 consecutive output cols -> vectorized
// epilogue (b64 bf16 / b128 fp32 stores, float4 bias+residual loads).
// flags: 1=gelu, 2=bf16 out
template<int BNt>
__global__ __launch_bounds__(256)
void gemm_bf16_t(const ushort_t* __restrict__ A, const ushort_t* __restrict__ Bt,
                 const float* __restrict__ bias, const float* __restrict__ residual,
                 void* __restrict__ C, int M, int N, int K, int flags)
{
    __shared__ ushort_t AsL[2][128 * 32];
    __shared__ ushort_t BsL[2][BNt * 32];
    int bm = blockIdx.y * 128;
    int bn = blockIdx.x * BNt;
    int tid = threadIdx.x;
    int lane = tid & 63;
    int wave = tid >> 6;
    int wm = wave >> 1, wn = wave & 1;
    int quad = lane >> 4, l15 = lane & 15;
    constexpr int NJ = BNt / 32;

    int srow = lane >> 2;
    int sg8 = ((lane & 3) ^ ((lane >> 3) & 3)) * 8;
    int fsw = (l15 >> 1) & 3;

    f32x4 acc[4][NJ];
    #pragma unroll
    for (int i = 0; i < 4; ++i)
        #pragma unroll
        for (int j = 0; j < NJ; ++j)
            acc[i][j] = (f32x4){0.f, 0.f, 0.f, 0.f};

    int iters = K / 32;
    llds16(&AsL[0][wave * 512], A + (size_t)(bm + wave * 16 + srow) * K + sg8);
    llds16(&AsL[0][(wave + 4) * 512], A + (size_t)(bm + (wave + 4) * 16 + srow) * K + sg8);
    llds16(&BsL[0][wave * 512], Bt + (size_t)(bn + wave * 16 + srow) * K + sg8);
    if (BNt == 128)
        llds16(&BsL[0][(wave + 4) * 512], Bt + (size_t)(bn + (wave + 4) * 16 + srow) * K + sg8);

    for (int kt = 0; kt < iters; ++kt) {
        int cur = kt & 1;
        __syncthreads();

        bf16x8 af[4], bfr[NJ];
        #pragma unroll
        for (int i = 0; i < 4; ++i)
            af[i] = *(const bf16x8*)&AsL[cur][(wm * 64 + i * 16 + l15) * 32 + ((quad ^ fsw) * 8)];
        #pragma unroll
        for (int j = 0; j < NJ; ++j)
            bfr[j] = *(const bf16x8*)&BsL[cur][(wn * (BNt / 2) + j * 16 + l15) * 32 + ((quad ^ fsw) * 8)];

        if (kt + 1 < iters) {
            int k0 = (kt + 1) * 32;
            int nxt = 1 - cur;
            llds16(&AsL[nxt][wave * 512], A + (size_t)(bm + wave * 16 + srow) * K + k0 + sg8);
            llds16(&AsL[nxt][(wave + 4) * 512], A + (size_t)(bm + (wave + 4) * 16 + srow) * K + k0 + sg8);
            llds16(&BsL[nxt][wave * 512], Bt + (size_t)(bn + wave * 16 + srow) * K + k0 + sg8);
            if (BNt == 128)
                llds16(&BsL[nxt][(wave + 4) * 512], Bt + (size_t)(bn + (wave + 4) * 16 + srow) * K + k0 + sg8);
        }

        // swapped operands: lane = A row (output row), quad*4+r = B row (output col)
        #pragma unroll
        for (int i = 0; i < 4; ++i)
            #pragma unroll
            for (int j = 0; j < NJ; ++j)
                acc[i][j] = MFMA16(bfr[j], af[i], acc[i][j]);
    }

    #pragma unroll
    for (int i = 0; i < 4; ++i) {
        int row = bm + wm * 64 + i * 16 + l15;
        #pragma unroll
        for (int j = 0; j < NJ; ++j) {
            int col = bn + wn * (BNt / 2) + j * 16 + quad * 4;
            float4 bia = *(const float4*)&bias[col];
            float o0 = acc[i][j][0] + bia.x;
            float o1 = acc[i][j][1] + bia.y;
            float o2 = acc[i][j][2] + bia.z;
            float o3 = acc[i][j][3] + bia.w;
            if (flags & 1) {
                o0 = o0 * 0.5f * (1.0f + erff(o0 * 0.70710678f));
                o1 = o1 * 0.5f * (1.0f + erff(o1 * 0.70710678f));
                o2 = o2 * 0.5f * (1.0f + erff(o2 * 0.70710678f));
                o3 = o3 * 0.5f * (1.0f + erff(o3 * 0.70710678f));
            }
            if (residual) {
                float4 rs = *(const float4*)&residual[(size_t)row * N + col];
                o0 += rs.x; o1 += rs.y; o2 += rs.z; o3 += rs.w;
            }
            if (flags & 2) {
                *(uint2*)&((ushort_t*)C)[(size_t)row * N + col] =
                    make_uint2(pack2bf(o0, o1), pack2bf(o2, o3));
            } else {
                *(float4*)&((float*)C)[(size_t)row * N + col] =
                    make_float4(o0, o1, o2, o3);
            }
        }
    }
}

// ---------------------------------------------------------------- dual o-projection
// Two sequential dbuf K-loops, swapped-operand MFMA, vectorized masked epilogue:
// x1 = x + (fg ? vg : (bgwin ? vl : 0)). BM=128, BN=64, K=768.
__global__ __launch_bounds__(256)
void oproj_dual_kernel(const ushort_t* __restrict__ ctxg, const ushort_t* __restrict__ ctxl,
                       const ushort_t* __restrict__ Wg, const ushort_t* __restrict__ Wl,
                       const float* __restrict__ biasg, const float* __restrict__ biasl,
                       const float* __restrict__ x, float* __restrict__ x1,
                       const float* __restrict__ fg, const float* __restrict__ bgw)
{
    __shared__ ushort_t AsL[2][128 * 32];
    __shared__ ushort_t BsL[2][64 * 32];
    int bm = blockIdx.y * 128;
    int bn = blockIdx.x * 64;
    int tid = threadIdx.x;
    int lane = tid & 63;
    int wave = tid >> 6;
    int wm = wave >> 1, wn = wave & 1;
    int quad = lane >> 4, l15 = lane & 15;

    int srow = lane >> 2;
    int sg8 = ((lane & 3) ^ ((lane >> 3) & 3)) * 8;
    int fsw = (l15 >> 1) & 3;
    const int K = Ch, N = Ch, iters = Ch / 32;

    f32x4 accg[4][2], accl[4][2];
    #pragma unroll
    for (int i = 0; i < 4; ++i)
        #pragma unroll
        for (int j = 0; j < 2; ++j) {
            accg[i][j] = (f32x4){0.f, 0.f, 0.f, 0.f};
            accl[i][j] = (f32x4){0.f, 0.f, 0.f, 0.f};
        }

    #pragma unroll
    for (int pass = 0; pass < 2; ++pass) {
        const ushort_t* A = pass ? ctxl : ctxg;
        const ushort_t* Bt = pass ? Wl : Wg;
        if (pass) __syncthreads();
        llds16(&AsL[0][wave * 512], A + (size_t)(bm + wave * 16 + srow) * K + sg8);
        llds16(&AsL[0][(wave + 4) * 512], A + (size_t)(bm + (wave + 4) * 16 + srow) * K + sg8);
        llds16(&BsL[0][wave * 512], Bt + (size_t)(bn + wave * 16 + srow) * K + sg8);

        for (int kt = 0; kt < iters; ++kt) {
            int cur = kt & 1;
            __syncthreads();
            bf16x8 af[4], bfr[2];
            #pragma unroll
            for (int i = 0; i < 4; ++i)
                af[i] = *(const bf16x8*)&AsL[cur][(wm * 64 + i * 16 + l15) * 32 + ((quad ^ fsw) * 8)];
            #pragma unroll
            for (int j = 0; j < 2; ++j)
                bfr[j] = *(const bf16x8*)&BsL[cur][(wn * 32 + j * 16 + l15) * 32 + ((quad ^ fsw) * 8)];
            if (kt + 1 < iters) {
                int k0 = (kt + 1) * 32;
                int nxt = 1 - cur;
                llds16(&AsL[nxt][wave * 512], A + (size_t)(bm + wave * 16 + srow) * K + k0 + sg8);
                llds16(&AsL[nxt][(wave + 4) * 512], A + (size_t)(bm + (wave + 4) * 16 + srow) * K + k0 + sg8);
                llds16(&BsL[nxt][wave * 512], Bt + (size_t)(bn + wave * 16 + srow) * K + k0 + sg8);
            }
            if (pass == 0) {
                #pragma unroll
                for (int i = 0; i < 4; ++i)
                    #pragma unroll
                    for (int j = 0; j < 2; ++j)
                        accg[i][j] = MFMA16(bfr[j], af[i], accg[i][j]);
            } else {
                #pragma unroll
                for (int i = 0; i < 4; ++i)
                    #pragma unroll
                    for (int j = 0; j < 2; ++j)
                        accl[i][j] = MFMA16(bfr[j], af[i], accl[i][j]);
            }
        }
    }

    #pragma unroll
    for (int i = 0; i < 4; ++i) {
        int row = bm + wm * 64 + i * 16 + l15;
        int bb = (row >= Lh) ? 1 : 0;
        int n = row - bb * Lh;
        int ii = n / 48, jj = n % 48;
        float keepg = (fg[row] != 0.0f) ? 1.0f : 0.0f;
        float keepl = (keepg == 0.0f &&
                       bgw[bb * 36 + (ii >> 3) * 6 + (jj >> 3)] != 0.0f) ? 1.0f : 0.0f;
        #pragma unroll
        for (int j = 0; j < 2; ++j) {
            int col = bn + wn * 32 + j * 16 + quad * 4;
            float4 bg4 = *(const float4*)&biasg[col];
            float4 bl4 = *(const float4*)&biasl[col];
            float4 x4 = *(const float4*)&x[(size_t)row * N + col];
            float4 o;
            o.x = x4.x + keepg * (accg[i][j][0] + bg4.x) + keepl * (accl[i][j][0] + bl4.x);
            o.y = x4.y + keepg * (accg[i][j][1] + bg4.y) + keepl * (accl[i][j][1] + bl4.y);
            o.z = x4.z + keepg * (accg[i][j][2] + bg4.z) + keepl * (accl[i][j][2] + bl4.z);
            o.w = x4.w + keepg * (accg[i][j][3] + bg4.w) + keepl * (accl[i][j][3] + bl4.w);
            *(float4*)&x1[(size_t)row * N + col] = o;
        }
    }
}

// ---------------------------------------------------------------- fused attention (global + local)
// S^T trick (R9) + PV operand swap: output lane = q, quad*4+r = 4 consecutive d
// -> b64 O-stores, no lbuf broadcast (l is per-lane q after butterfly reduce).
__device__ __forceinline__ void attn_global_body(
    const ushort_t* __restrict__ QKV, const float* __restrict__ fg,
    ushort_t* __restrict__ O, int tile, int h, int b,
    ushort_t (*Ks)[72], ushort_t (*Vt)[72], ushort_t (*Ps)[72], float* fgs)
{
    int tid = threadIdx.x;
    int lane = tid & 63;
    int wave = tid >> 6;
    int quad = lane >> 4, l15 = lane & 15;

    bf16x8 aq[2][2];
    #pragma unroll
    for (int s = 0; s < 2; ++s) {
        int ql = wave * 32 + s * 16 + l15;
        int tok = tile * 128 + ql;
        const ushort_t* qbase = QKV + (size_t)(b * Lh + tok) * QS + h * 64;
        #pragma unroll
        for (int step = 0; step < 2; ++step)
            aq[s][step] = *(const bf16x8*)(qbase + step * 32 + quad * 8);
    }

    float l_part[2] = {0.f, 0.f};
    f32x4 o_acc[2][4];
    #pragma unroll
    for (int s = 0; s < 2; ++s)
        #pragma unroll
        for (int t4 = 0; t4 < 4; ++t4) o_acc[s][t4] = (f32x4){0.f, 0.f, 0.f, 0.f};

    uint4 kx[2], vx[2];
    #pragma unroll
    for (int it = 0; it < 2; ++it) {
        int e = tid + it * 256;
        int row = e >> 3, g = e & 7;
        const ushort_t* base = QKV + (size_t)(b * Lh + row) * QS + h * 64 + g * 8;
        kx[it] = *(const uint4*)(base + 768);
        vx[it] = *(const uint4*)(base + 1536);
    }
    float fgn = 0.f;
    if (tid < 64) fgn = fg[b * Lh + tid];

    for (int kt = 0; kt < 36; ++kt) {
        __syncthreads();
        #pragma unroll
        for (int it = 0; it < 2; ++it) {
            int e = tid + it * 256;
            int row = e >> 3, g = e & 7;
            *(uint4*)&Ks[row][g * 8] = kx[it];
            union { uint4 raw; ushort_t us[8]; } vv;
            vv.raw = vx[it];
            int col = row ^ (g << 3);
            #pragma unroll
            for (int j = 0; j < 8; ++j) Vt[g * 8 + j][col] = vv.us[j];
        }
        if (tid < 64) fgs[tid] = (fgn - 1.0f) * 1e9f;
        __syncthreads();

        if (kt + 1 < 36) {
            #pragma unroll
            for (int it = 0; it < 2; ++it) {
                int e = tid + it * 256;
                int row = e >> 3, g = e & 7;
                int tok = (kt + 1) * 64 + row;
                const ushort_t* base = QKV + (size_t)(b * Lh + tok) * QS + h * 64 + g * 8;
                kx[it] = *(const uint4*)(base + 768);
                vx[it] = *(const uint4*)(base + 1536);
            }
            if (tid < 64) fgn = fg[b * Lh + (kt + 1) * 64 + tid];
        }

        f32x4 s4[2][4];
        #pragma unroll
        for (int s = 0; s < 2; ++s)
            #pragma unroll
            for (int j4 = 0; j4 < 4; ++j4) s4[s][j4] = (f32x4){0.f, 0.f, 0.f, 0.f};
        #pragma unroll
        for (int step = 0; step < 2; ++step) {
            bf16x8 bk[4];
            #pragma unroll
            for (int j4 = 0; j4 < 4; ++j4)
                bk[j4] = *(const bf16x8*)&Ks[j4 * 16 + l15][step * 32 + quad * 8];
            #pragma unroll
            for (int s = 0; s < 2; ++s)
                #pragma unroll
                for (int j4 = 0; j4 < 4; ++j4)
                    s4[s][j4] = MFMA16(bk[j4], aq[s][step], s4[s][j4]);
        }
        #pragma unroll
        for (int s = 0; s < 2; ++s) {
            int p0 = wave * 32 + s * 16;
            #pragma unroll
            for (int j4 = 0; j4 < 4; ++j4) {
                float4 mb4 = *(const float4*)&fgs[j4 * 16 + quad * 4];
                float e0 = __expf(s4[s][j4][0] * 0.125f + mb4.x);
                float e1 = __expf(s4[s][j4][1] * 0.125f + mb4.y);
                float e2 = __expf(s4[s][j4][2] * 0.125f + mb4.z);
                float e3 = __expf(s4[s][j4][3] * 0.125f + mb4.w);
                l_part[s] += (e0 + e1) + (e2 + e3);
                uint_t a01 = __builtin_amdgcn_perm(__float_as_uint(e1), __float_as_uint(e0), 0x07060302u);
                uint_t a23 = __builtin_amdgcn_perm(__float_as_uint(e3), __float_as_uint(e2), 0x07060302u);
                *(uint2*)&Ps[p0 + l15][j4 * 16 + quad * 4] = make_uint2(a01, a23);
            }
        }
        #pragma unroll
        for (int step = 0; step < 2; ++step) {
            bf16x8 bv[4];
            #pragma unroll
            for (int t4 = 0; t4 < 4; ++t4) {
                int dd = t4 * 16 + l15;
                int cb = ((step * 4 + quad) ^ ((dd >> 3) & 7)) * 8;
                bv[t4] = *(const bf16x8*)&Vt[dd][cb];
            }
            #pragma unroll
            for (int s = 0; s < 2; ++s) {
                int p0 = wave * 32 + s * 16;
                bf16x8 a = *(const bf16x8*)&Ps[p0 + l15][step * 32 + quad * 8];
                #pragma unroll
                for (int t4 = 0; t4 < 4; ++t4)
                    o_acc[s][t4] = MFMA16(bv[t4], a, o_acc[s][t4]);   // swapped: lane=q
            }
        }
    }

    // l: butterfly reduce across quads -> every lane has full sum for its q=l15
    #pragma unroll
    for (int s = 0; s < 2; ++s) {
        float v = l_part[s];
        v += __shfl_xor(v, 16, 64);
        v += __shfl_xor(v, 32, 64);
        float inv = 1.0f / v;
        int ql = wave * 32 + s * 16 + l15;
        int tok = tile * 128 + ql;
        ushort_t* ob = O + (size_t)(b * Lh + tok) * Ch + h * 64;
        #pragma unroll
        for (int t4 = 0; t4 < 4; ++t4) {
            *(uint2*)&ob[t4 * 16 + quad * 4] =
                make_uint2(pack2bf(o_acc[s][t4][0] * inv, o_acc[s][t4][1] * inv),
                           pack2bf(o_acc[s][t4][2] * inv, o_acc[s][t4][3] * inv));
        }
    }
}

__device__ __forceinline__ void attn_local_body(
    const ushort_t* __restrict__ QKV, ushort_t* __restrict__ O,
    int tile, int h, int b,
    ushort_t (*Ks)[72], ushort_t (*Vt)[72], ushort_t (*Ps)[72])
{
    int tid = threadIdx.x;
    int lane = tid & 63;
    int wave = tid >> 6;
    int quad = lane >> 4, l15 = lane & 15;
    int wi = tile / 6, wj = tile % 6;

    bf16x8 aq[2];
    {
        int ql = wave * 16 + l15;
        int tok = (wi * 8 + (ql >> 3)) * 48 + wj * 8 + (ql & 7);
        const ushort_t* qbase = QKV + (size_t)(b * Lh + tok) * QS + 2304 + h * 64;
        #pragma unroll
        for (int step = 0; step < 2; ++step)
            aq[step] = *(const bf16x8*)(qbase + step * 32 + quad * 8);
    }

    float l_part = 0.f;
    f32x4 o_acc[4];
    #pragma unroll
    for (int t4 = 0; t4 < 4; ++t4) o_acc[t4] = (f32x4){0.f, 0.f, 0.f, 0.f};

    #pragma unroll
    for (int it = 0; it < 2; ++it) {
        int e = tid + it * 256;
        int row = e >> 3, g = e & 7;
        int tok = (wi * 8 + (row >> 3)) * 48 + wj * 8 + (row & 7);
        const ushort_t* base = QKV + (size_t)(b * Lh + tok) * QS + 2304 + h * 64 + g * 8;
        uint4 kvv = *(const uint4*)(base + 768);
        *(uint4*)&Ks[row][g * 8] = kvv;
        union { uint4 raw; ushort_t us[8]; } vv;
        vv.raw = *(const uint4*)(base + 1536);
        int col = row ^ (g << 3);
        #pragma unroll
        for (int j = 0; j < 8; ++j) Vt[g * 8 + j][col] = vv.us[j];
    }
    __syncthreads();

    f32x4 s4[4];
    #pragma unroll
    for (int j4 = 0; j4 < 4; ++j4) s4[j4] = (f32x4){0.f, 0.f, 0.f, 0.f};
    #pragma unroll
    for (int step = 0; step < 2; ++step) {
        bf16x8 bk[4];
        #pragma unroll
        for (int j4 = 0; j4 < 4; ++j4)
            bk[j4] = *(const bf16x8*)&Ks[j4 * 16 + l15][step * 32 + quad * 8];
        #pragma unroll
        for (int j4 = 0; j4 < 4; ++j4)
            s4[j4] = MFMA16(bk[j4], aq[step], s4[j4]);
    }
    int p0 = wave * 16;
    #pragma unroll
    for (int j4 = 0; j4 < 4; ++j4) {
        float e0 = __expf(s4[j4][0] * 0.125f);
        float e1 = __expf(s4[j4][1] * 0.125f);
        float e2 = __expf(s4[j4][2] * 0.125f);
        float e3 = __expf(s4[j4][3] * 0.125f);
        l_part += (e0 + e1) + (e2 + e3);
        uint_t a01 = __builtin_amdgcn_perm(__float_as_uint(e1), __float_as_uint(e0), 0x07060302u);
        uint_t a23 = __builtin_amdgcn_perm(__float_as_uint(e3), __float_as_uint(e2), 0x07060302u);
        *(uint2*)&Ps[p0 + l15][j4 * 16 + quad * 4] = make_uint2(a01, a23);
    }
    #pragma unroll
    for (int step = 0; step < 2; ++step) {
        bf16x8 bv[4];
        #pragma unroll
        for (int t4 = 0; t4 < 4; ++t4) {
            int dd = t4 * 16 + l15;
            int cb = ((step * 4 + quad) ^ ((dd >> 3) & 7)) * 8;
            bv[t4] = *(const bf16x8*)&Vt[dd][cb];
        }
        bf16x8 a = *(const bf16x8*)&Ps[p0 + l15][step * 32 + quad * 8];
        #pragma unroll
        for (int t4 = 0; t4 < 4; ++t4)
            o_acc[t4] = MFMA16(bv[t4], a, o_acc[t4]);   // swapped: lane=q
    }

    {
        float v = l_part;
        v += __shfl_xor(v, 16, 64);
        v += __shfl_xor(v, 32, 64);
        float inv = 1.0f / v;
        int ql = wave * 16 + l15;
        int tok = (wi * 8 + (ql >> 3)) * 48 + wj * 8 + (ql & 7);
        ushort_t* ob = O + (size_t)(b * Lh + tok) * Ch + h * 64;
        #pragma unroll
        for (int t4 = 0; t4 < 4; ++t4) {
            *(uint2*)&ob[t4 * 16 + quad * 4] =
                make_uint2(pack2bf(o_acc[t4][0] * inv, o_acc[t4][1] * inv),
                           pack2bf(o_acc[t4][2] * inv, o_acc[t4][3] * inv));
        }
    }
}

__global__ __launch_bounds__(256)
void attn_fused_kernel(const ushort_t* __restrict__ QKV, const float* __restrict__ fg,
                       ushort_t* __restrict__ ctxg, ushort_t* __restrict__ ctxl)
{
    __shared__ ushort_t Ks[64][72];
    __shared__ ushort_t Vt[64][72];
    __shared__ ushort_t Ps[128][72];
    __shared__ float fgs[64];

    int gid = blockIdx.x;
    if (gid < 432) {
        int tile = gid % 18;
        int h = (gid / 18) % NHh;
        int b = gid / (18 * NHh);
        attn_global_body(QKV, fg, ctxg, tile, h, b, Ks, Vt, Ps, fgs);
    } else {
        int rr = gid - 432;
        int tile = rr % 36;
        int h = (rr / 36) % NHh;
        int b = rr / (36 * NHh);
        attn_local_body(QKV, ctxl, tile, h, b, Ks, Vt, Ps);
    }
}

// ---------------------------------------------------------------- launch
extern "C" void kernel_launch(void* const* d_in, const int* in_sizes, int n_in,
                              void* d_out, int out_size, void* d_ws, size_t ws_size,
                              hipStream_t stream)
{
    const float* x       = (const float*)d_in[0];
    const float* mask    = (const float*)d_in[1];
    const float* w_qkv_g = (const float*)d_in[2];
    const float* b_qkv_g = (const float*)d_in[3];
    const float* w_o_g   = (const float*)d_in[4];
    const float* b_o_g   = (const float*)d_in[5];
    const float* w_qkv_l = (const float*)d_in[6];
    const float* b_qkv_l = (const float*)d_in[7];
    const float* w_o_l   = (const float*)d_in[8];
    const float* b_o_l   = (const float*)d_in[9];
    const float* ln1_w   = (const float*)d_in[10];
    const float* ln1_b   = (const float*)d_in[11];
    const float* ln2_w   = (const float*)d_in[12];
    const float* ln2_b   = (const float*)d_in[13];
    const float* w_fc1   = (const float*)d_in[14];
    const float* b_fc1   = (const float*)d_in[15];
    const float* w_fc2   = (const float*)d_in[16];
    const float* b_fc2   = (const float*)d_in[17];
    float* out = (float*)d_out;

    const size_t U = (size_t)Bh * Lh * Ch;           // 3,538,944
    char* p = (char*)d_ws;
    ushort_t* qkvb = (ushort_t*)p;        p += (size_t)4608 * 4608 * 2;  // [4608][4608] bf16
    ushort_t* midb = qkvb;                                               // [4608][3072] aliases
    ushort_t* ctxg = (ushort_t*)p;        p += U * 2;
    ushort_t* ctxl = (ushort_t*)p;        p += U * 2;
    ushort_t* xnb  = (ushort_t*)p;        p += U * 2;
    float*    x1   = (float*)p;           p += U * 4;
    ushort_t* wtq  = (ushort_t*)p;        p += (size_t)4608 * 768 * 2;   // qkv g|l concat
    ushort_t* wt_o_g = (ushort_t*)p;      p += (size_t)768 * 768 * 2;
    ushort_t* wt_o_l = (ushort_t*)p;      p += (size_t)768 * 768 * 2;
    ushort_t* wt_fc1 = (ushort_t*)p;      p += (size_t)3072 * 768 * 2;
    ushort_t* wt_fc2 = (ushort_t*)p;      p += (size_t)768 * 3072 * 2;
    float*    biasq  = (float*)p;         p += 4608 * 4;
    float*    fg     = (float*)p;         p += Bh * Lh * 4;
    float*    bgw    = (float*)p;

    const int Mrows = Bh * Lh;                   // 4608
    dim3 blk(256);

    hipMemcpyAsync(biasq, b_qkv_g, 2304 * sizeof(float), hipMemcpyDeviceToDevice, stream);
    hipMemcpyAsync(biasq + 2304, b_qkv_l, 2304 * sizeof(float), hipMemcpyDeviceToDevice, stream);

    transpose_all_kernel<<<2304, blk, 0, stream>>>(
        w_qkv_g, w_qkv_l, w_o_g, w_o_l, w_fc1, w_fc2,
        wtq, wt_o_g, wt_o_l, wt_fc1, wt_fc2);

    layernorm_bf16_kernel<<<Mrows, blk, 0, stream>>>(x, ln1_w, ln1_b, xnb);
    mask_kernel<<<72, dim3(64), 0, stream>>>(mask, fg, bgw);

    // fused QKV GEMM for both branches (N=4608)
    gemm_bf16_t<128><<<dim3(4608 / 128, Mrows / 128), blk, 0, stream>>>(
        xnb, wtq, biasq, nullptr, qkvb, Mrows, 4608, Ch, 2);

    // fused attention: 432 global + 864 local blocks
    attn_fused_kernel<<<1296, blk, 0, stream>>>(qkvb, fg, ctxg, ctxl);

    // dual masked o-projection -> x1 (one dispatch)
    oproj_dual_kernel<<<dim3(Ch / 64, Mrows / 128), blk, 0, stream>>>(
        ctxg, ctxl, wt_o_g, wt_o_l, b_o_g, b_o_l, x, x1, fg, bgw);

    layernorm_bf16_kernel<<<Mrows, blk, 0, stream>>>(x1, ln2_w, ln2_b, xnb);

    // MLP
    gemm_bf16_t<128><<<dim3(3072 / 128, Mrows / 128), blk, 0, stream>>>(
        xnb, wt_fc1, b_fc1, nullptr, midb, Mrows, 3072, Ch, 1 | 2);
    gemm_bf16_t<64><<<dim3(Ch / 64, Mrows / 128), blk, 0, stream>>>(
        midb, wt_fc2, b_fc2, x1, out, Mrows, Ch, 3072, 0);
}